// Round 6
// baseline (48640.509 us; speedup 1.0000x reference)
//
#include <hip/hip_runtime.h>
#include <math.h>

// ---------------- problem dims ----------------
#define VV 32000
#define HH 512
#define G3 1536   // 3*HH
#define TI 128    // encoder length
#define TO 64     // max decode length
#define NB 5      // beam width
#define NEGF (-1000000000.0f)

// ---------------- grid config ----------------
#define NWG 256
#define NTHR 256
#define KGRU 64   // WGs running encoder recurrence + decoder GRU
#define KPA 40    // WGs running attention+Wc phase (8 per beam)

struct Params {
  const int* seq;
  const int* sosp;
  const float *emb, *eWi, *eWh, *ebi, *ebh;
  const float *dWi, *dWh, *dbi, *dbh;
  const float *Wc, *bc, *Wout, *bout;
  unsigned* bar;
  int *cur_tok, *toks, *pars, *ptop_i;
  float *gi0, *eout, *h0b, *h1b, *dch, *cc, *ptop_v, *psum, *scores;
  float* out;
};

// ---- round-2-validated sync primitives (plain data + fence/add, acquire-poll) ----
__device__ __forceinline__ void xarrive(unsigned* c) {
  __syncthreads();                      // all WG stores issued & vm-drained
  if (threadIdx.x == 0) {
    __threadfence();                    // release: writeback to coherence point
    atomicAdd(c, 1u);                   // device-scope
  }
}
template <int SLP>
__device__ __forceinline__ void xwait(unsigned* c, unsigned target) {
  if (threadIdx.x == 0) {
    while (__hip_atomic_load(c, __ATOMIC_ACQUIRE, __HIP_MEMORY_SCOPE_AGENT) < target)
      __builtin_amdgcn_s_sleep(SLP);
    __threadfence();                    // acquire side: invalidate stale caches
  }
  __syncthreads();
}
template <int SLP>
__device__ __forceinline__ void xbar(unsigned* c, unsigned target) {
  xarrive(c);
  xwait<SLP>(c, target);
}

__device__ __forceinline__ float wredf(float v) {
#pragma unroll
  for (int o = 32; o; o >>= 1) v += __shfl_xor(v, o, 64);
  return v;
}

// Decoder GRU layer over KGRU WGs, weights register-resident. Plain mem ops.
template <int LAYER>
__device__ void dec_gru_reg(const Params& p, float* sm, int t, int ib, int ob,
                            const float (&wd)[12][8]) {
  const int wg = blockIdx.x, tid = threadIdx.x;
  const int lane = tid & 63, wv = tid >> 6;
  float* sx = sm;                 // [NB][HH]
  float* sh = sm + NB * HH;       // [NB][HH]
  float* fres = sm + 2 * NB * HH; // [48][NB]

  for (int i = tid; i < NB * HH; i += NTHR) {
    int b = i / HH, u = i - b * HH;
    float xv;
    if (LAYER == 0) xv = p.emb[(size_t)p.cur_tok[b] * HH + u];
    else            xv = p.dch[((size_t)(ob * 2 + 0) * NB + b) * HH + u];
    sx[i] = xv;
    int pb = (t == 0) ? b : p.pars[(t - 1) * NB + b];
    sh[i] = p.dch[((size_t)(ib * 2 + LAYER) * NB + pb) * HH + u];
  }
  __syncthreads();
#pragma unroll
  for (int k = 0; k < 12; k++) {
    const int m_ = k % 6;                  // f%6 == k%6 since f = wv*12 + k
    const int f = wv * 12 + k;
    const float* vecb = (m_ >= 3) ? sh : sx;
    float a0 = 0.f, a1 = 0.f, a2 = 0.f, a3 = 0.f, a4 = 0.f;
#pragma unroll
    for (int j = 0; j < 8; j++) {
      float wj = wd[k][j];
      int o = j * 64 + lane;
      a0 += wj * vecb[0 * HH + o];
      a1 += wj * vecb[1 * HH + o];
      a2 += wj * vecb[2 * HH + o];
      a3 += wj * vecb[3 * HH + o];
      a4 += wj * vecb[4 * HH + o];
    }
    float r0 = wredf(a0), r1 = wredf(a1), r2 = wredf(a2), r3 = wredf(a3), r4 = wredf(a4);
    if (lane == 0) {
      fres[f * NB + 0] = r0; fres[f * NB + 1] = r1; fres[f * NB + 2] = r2;
      fres[f * NB + 3] = r3; fres[f * NB + 4] = r4;
    }
  }
  __syncthreads();
  if (tid < 8 * NB) {
    int ul = tid / NB, b = tid - ul * NB;
    int u = wg * 8 + ul;
    const float* bi = p.dbi + LAYER * G3;
    const float* bh = p.dbh + LAYER * G3;
    float ir = fres[(ul * 6 + 0) * NB + b] + bi[u];
    float iz = fres[(ul * 6 + 1) * NB + b] + bi[HH + u];
    float inn = fres[(ul * 6 + 2) * NB + b] + bi[2 * HH + u];
    float hr = fres[(ul * 6 + 3) * NB + b] + bh[u];
    float hz = fres[(ul * 6 + 4) * NB + b] + bh[HH + u];
    float hn = fres[(ul * 6 + 5) * NB + b] + bh[2 * HH + u];
    float hp = sh[b * HH + u];
    float r = 1.f / (1.f + expf(-(ir + hr)));
    float z = 1.f / (1.f + expf(-(iz + hz)));
    float n = tanhf(inn + r * hn);
    p.dch[((size_t)(ob * 2 + LAYER) * NB + b) * HH + u] = (1.f - z) * n + z * hp;
  }
}

__global__ void __launch_bounds__(NTHR, 1) bsd_kernel(Params p) {
  const int wg = blockIdx.x, tid = threadIdx.x;
  const int lane = tid & 63, wv = tid >> 6;
  __shared__ float sm[5504];

  unsigned* c_grid = p.bar + 0;
  unsigned* c_enc  = p.bar + 16;
  unsigned* c1     = p.bar + 32;
  unsigned* c2     = p.bar + 48;
  unsigned* c3     = p.bar + 64;
  unsigned* c5     = p.bar + 80;
  unsigned* flag6  = p.bar + 96;
  unsigned* fenc   = p.bar + 112;

  // ========== E0: gi0[t][row] = emb[seq[t]] . eWi0[row] + ebi0[row]; zero h ==========
  {
    if (wg == 0) {
      for (int i = tid; i < 2 * HH; i += NTHR) { p.h0b[i] = 0.f; p.h1b[i] = 0.f; }
    }
    for (int lr = wv; lr < 6; lr += 4) {
      int row = wg * 6 + lr;
      const float* W = p.eWi + (size_t)row * HH;
      float w0[8];
#pragma unroll
      for (int j = 0; j < 8; j++) w0[j] = W[j * 64 + lane];
      float bi = p.ebi[row];
      for (int t = 0; t < TI; t++) {
        const float* x = p.emb + (size_t)p.seq[t] * HH;
        float s = 0.f;
#pragma unroll
        for (int j = 0; j < 8; j++) s += w0[j] * x[j * 64 + lane];
        s = wredf(s);
        if (lane == 0) p.gi0[(size_t)t * G3 + row] = s + bi;
      }
    }
  }
  xbar<2>(c_grid, NWG);

  // ========== E1: recurrence on KGRU WGs, register weights, 129 mini-barriers ==========
  if (wg < KGRU) {
    float wreg[24][8];  // L0 waves: rows [uu*3+g]; L1 waves: rows [uu*6+mg]
    if (wv < 2) {
#pragma unroll
      for (int uu = 0; uu < 4; uu++) {
        int u = wg * 8 + wv * 4 + uu;
#pragma unroll
        for (int g = 0; g < 3; g++) {
          const float* W = p.eWh + (size_t)(g * HH + u) * HH;
#pragma unroll
          for (int j = 0; j < 8; j++) wreg[uu * 3 + g][j] = W[j * 64 + lane];
        }
      }
    } else {
#pragma unroll
      for (int uu = 0; uu < 4; uu++) {
        int u = wg * 8 + (wv - 2) * 4 + uu;
#pragma unroll
        for (int g = 0; g < 3; g++) {
          const float* Wi1 = p.eWi + (size_t)G3 * HH + (size_t)(g * HH + u) * HH;
          const float* Wh1 = p.eWh + (size_t)G3 * HH + (size_t)(g * HH + u) * HH;
#pragma unroll
          for (int j = 0; j < 8; j++) {
            wreg[uu * 6 + g][j] = Wi1[j * 64 + lane];
            wreg[uu * 6 + 3 + g][j] = Wh1[j * 64 + lane];
          }
        }
      }
    }
    for (int T = 0; T <= TI; T++) {
      const int sIn = T & 1, sOut = sIn ^ 1;
      if (wv < 2) {
        if (T < TI) {
          const float* hprev = p.h0b + sIn * HH;
          float hv[8];
#pragma unroll
          for (int j = 0; j < 8; j++) hv[j] = hprev[j * 64 + lane];
#pragma unroll
          for (int uu = 0; uu < 4; uu++) {
            int u = wg * 8 + wv * 4 + uu;
            float g[3];
#pragma unroll
            for (int gg = 0; gg < 3; gg++) {
              float s = 0.f;
#pragma unroll
              for (int j = 0; j < 8; j++) s += wreg[uu * 3 + gg][j] * hv[j];
              g[gg] = wredf(s);
            }
            if (lane == 0) {
              const float* gr = p.gi0 + (size_t)T * G3;
              float ir = gr[u], iz = gr[HH + u], inn = gr[2 * HH + u];
              float hr = g[0] + p.ebh[u], hz = g[1] + p.ebh[HH + u], hn = g[2] + p.ebh[2 * HH + u];
              float r = 1.f / (1.f + expf(-(ir + hr)));
              float z = 1.f / (1.f + expf(-(iz + hz)));
              float n = tanhf(inn + r * hn);
              p.h0b[sOut * HH + u] = (1.f - z) * n + z * hprev[u];
            }
          }
        }
      } else {
        if (T >= 1) {
          const float* xsrc = p.h0b + sIn * HH;
          const float* hprev = p.h1b + sOut * HH;
          float xv[8], hv[8];
#pragma unroll
          for (int j = 0; j < 8; j++) { xv[j] = xsrc[j * 64 + lane]; hv[j] = hprev[j * 64 + lane]; }
#pragma unroll
          for (int uu = 0; uu < 4; uu++) {
            int u = wg * 8 + (wv - 2) * 4 + uu;
            float gi[3], gh[3];
#pragma unroll
            for (int gg = 0; gg < 3; gg++) {
              float si = 0.f, s2 = 0.f;
#pragma unroll
              for (int j = 0; j < 8; j++) {
                si += wreg[uu * 6 + gg][j] * xv[j];
                s2 += wreg[uu * 6 + 3 + gg][j] * hv[j];
              }
              gi[gg] = wredf(si);
              gh[gg] = wredf(s2);
            }
            if (lane == 0) {
              const float* bi = p.ebi + G3;
              const float* bh = p.ebh + G3;
              float ir = gi[0] + bi[u], iz = gi[1] + bi[HH + u], inn = gi[2] + bi[2 * HH + u];
              float hr = gh[0] + bh[u], hz = gh[1] + bh[HH + u], hn = gh[2] + bh[2 * HH + u];
              float r = 1.f / (1.f + expf(-(ir + hr)));
              float z = 1.f / (1.f + expf(-(iz + hz)));
              float n = tanhf(inn + r * hn);
              float hnew = (1.f - z) * n + z * hprev[u];
              p.h1b[sIn * HH + u] = hnew;
              p.eout[(size_t)(T - 1) * HH + u] = hnew;
            }
          }
        }
      }
      xbar<1>(c_enc, (unsigned)(KGRU * (T + 1)));
    }
    if (wg == 0 && tid == 0) {
      __threadfence();
      __hip_atomic_store(fenc, 1u, __ATOMIC_RELEASE, __HIP_MEMORY_SCOPE_AGENT);
    }
  } else {
    xwait<8>(fenc, 1u);
  }

  // ---- load decoder GRU weights into registers (KGRU WGs), both layers ----
  float wdec[2][12][8];
  if (wg < KGRU) {
#pragma unroll
    for (int k = 0; k < 12; k++) {
      const int f = wv * 12 + k;
      const int ul = f / 6, m_ = f % 6;
      const int u = wg * 8 + ul;
      const float* W0 = (m_ < 3 ? p.dWi : p.dWh) + (size_t)((m_ % 3) * HH + u) * HH;
      const float* W1 = (m_ < 3 ? p.dWi : p.dWh) + (size_t)G3 * HH + (size_t)((m_ % 3) * HH + u) * HH;
#pragma unroll
      for (int j = 0; j < 8; j++) { wdec[0][k][j] = W0[j * 64 + lane]; wdec[1][k][j] = W1[j * 64 + lane]; }
    }
  }

  // ========== D0: broadcast enc_hidden to beams, init tokens/scores ==========
  {
    for (int i = tid + wg * NTHR; i < 2 * NB * HH; i += NWG * NTHR) {
      int l = i / (NB * HH);
      int rem = i - l * (NB * HH);
      int u = rem % HH;
      p.dch[(size_t)l * NB * HH + rem] = (l == 0) ? p.h0b[u] : p.h1b[u];
    }
    if (wg == 0 && tid < NB) {
      p.cur_tok[tid] = p.sosp[0];
      p.scores[tid] = (tid == 0) ? 0.f : NEGF;
    }
  }
  xbar<2>(c_grid, 2 * NWG);

  // ========== decoder: 64 steps ==========
  for (int t = 0; t < TO; t++) {
    const int ib = t & 1, ob = ib ^ 1;

    xwait<2>(flag6, (unsigned)t);  // step-t inputs (cur_tok/pars/scores) ready

    if (wg < KGRU) {
      dec_gru_reg<0>(p, sm, t, ib, ob, wdec[0]);
      xbar<1>(c1, (unsigned)(KGRU * (t + 1)));
      dec_gru_reg<1>(p, sm, t, ib, ob, wdec[1]);
      xbar<1>(c2, (unsigned)(KGRU * (t + 1)));
    }

    // ---- PA: attention + ctx + Wc + tanh (40 WGs, 8 per beam) ----
    if (wg < KPA) {
      const int b = wg / 8, q = wg % 8;
      float* srnn = sm;           // 512
      float* sp = sm + HH;        // 128 scores -> probs
      float* sctx = sm + HH + TI; // 512
      for (int i = tid; i < HH; i += NTHR)
        srnn[i] = p.dch[((size_t)(ob * 2 + 1) * NB + b) * HH + i];
      __syncthreads();
      for (int j = wv; j < TI; j += 4) {
        const float* E = p.eout + (size_t)j * HH;
        float s = 0.f;
#pragma unroll
        for (int k = 0; k < 8; k++) s += srnn[k * 64 + lane] * E[k * 64 + lane];
        s = wredf(s);
        if (lane == 0) sp[j] = s;
      }
      __syncthreads();
      if (wv == 0) {
        float v0 = sp[lane], v1 = sp[64 + lane];
        float mx = fmaxf(v0, v1);
#pragma unroll
        for (int o = 32; o; o >>= 1) mx = fmaxf(mx, __shfl_xor(mx, o, 64));
        float e0 = expf(v0 - mx), e1 = expf(v1 - mx);
        float ss = wredf(e0 + e1);
        sp[lane] = e0 / ss;
        sp[64 + lane] = e1 / ss;
      }
      __syncthreads();
      for (int u = tid; u < HH; u += NTHR) {
        float s = 0.f;
        for (int j = 0; j < TI; j++) s += sp[j] * p.eout[(size_t)j * HH + u];
        sctx[u] = s;
      }
      __syncthreads();
      for (int k = wv; k < 64; k += 4) {
        int u = q * 64 + k;
        const float* W = p.Wc + (size_t)u * (2 * HH);
        float s0 = 0.f, s1 = 0.f;
#pragma unroll
        for (int j = 0; j < 8; j++) {
          int o = j * 64 + lane;
          s0 += W[o] * srnn[o];
          s1 += W[HH + o] * sctx[o];
        }
        float r0 = wredf(s0), r1 = wredf(s1);
        if (lane == 0) p.cc[b * HH + u] = tanhf(r0 + r1 + p.bc[u]);
      }
      xarrive(c3);
    }
    xwait<2>(c3, (unsigned)(KPA * (t + 1)));

    // ---- P5: logits chunk (125 rows/WG) + per-beam partial top5 + exp-sum ----
    {
      float* scc = sm;            // [NB][HH]
      float* slg = sm + NB * HH;  // [NB][125]
      for (int i = tid; i < NB * HH; i += NTHR) scc[i] = p.cc[i];
      __syncthreads();
      const int vbase = wg * 125;
      for (int r = wv; r < 125; r += 4) {
        int v = vbase + r;
        const float* W = p.Wout + (size_t)v * HH;
        float w0[8];
#pragma unroll
        for (int j = 0; j < 8; j++) w0[j] = W[j * 64 + lane];
        float a0 = 0.f, a1 = 0.f, a2 = 0.f, a3 = 0.f, a4 = 0.f;
#pragma unroll
        for (int j = 0; j < 8; j++) {
          float wj = w0[j];
          int o = j * 64 + lane;
          a0 += wj * scc[0 * HH + o];
          a1 += wj * scc[1 * HH + o];
          a2 += wj * scc[2 * HH + o];
          a3 += wj * scc[3 * HH + o];
          a4 += wj * scc[4 * HH + o];
        }
        float r0 = wredf(a0), r1 = wredf(a1), r2 = wredf(a2), r3 = wredf(a3), r4 = wredf(a4);
        if (lane == 0) {
          float bo = p.bout[v];
          slg[0 * 125 + r] = r0 + bo;
          slg[1 * 125 + r] = r1 + bo;
          slg[2 * 125 + r] = r2 + bo;
          slg[3 * 125 + r] = r3 + bo;
          slg[4 * 125 + r] = r4 + bo;
        }
      }
      __syncthreads();
      if (wv == 0) {
        for (int b = 0; b < NB; b++) {
          float s0 = (lane < 125) ? expf(slg[b * 125 + lane]) : 0.f;
          float s1 = (lane + 64 < 125) ? expf(slg[b * 125 + lane + 64]) : 0.f;
          float ss = wredf(s0 + s1);
          if (lane == 0) p.psum[wg * NB + b] = ss;
        }
      } else if (wv == 1 && lane < NB) {
        int b = lane;
        float bv[5]; int bidx[5];
#pragma unroll
        for (int k = 0; k < 5; k++) { bv[k] = -INFINITY; bidx[k] = 0x7fffffff; }
        for (int r = 0; r < 125; r++) {
          float v = slg[b * 125 + r];
          if (v > bv[4]) {  // strict >: equal values keep earlier (lower) index
            int k = 4;
            while (k > 0 && v > bv[k - 1]) { bv[k] = bv[k - 1]; bidx[k] = bidx[k - 1]; k--; }
            bv[k] = v; bidx[k] = vbase + r;
          }
        }
#pragma unroll
        for (int k = 0; k < 5; k++) {
          p.ptop_v[(wg * NB + b) * 5 + k] = bv[k];
          p.ptop_i[(wg * NB + b) * 5 + k] = bidx[k];
        }
      }
    }
    xarrive(c5);

    // ---- P6: merge (WG 0): lse, global top5/beam, 25-cand top5, bookkeeping ----
    if (wg == 0) {
      xwait<2>(c5, (unsigned)(NWG * (t + 1)));
      float* sval = sm;                  // [256][5]
      int* sidx = (int*)(sm + 1280);     // [256][5]
      float* sls = sm + 2560;            // [5]
      float* smv = sm + 2576;            // [5][5]
      int* smi = (int*)(sm + 2608);      // [5][5]
      if (wv == 0) {
        for (int b = 0; b < NB; b++) {
          float q0 = p.psum[(lane + 0) * NB + b];
          float q1 = p.psum[(lane + 64) * NB + b];
          float q2 = p.psum[(lane + 128) * NB + b];
          float q3 = p.psum[(lane + 192) * NB + b];
          float s = wredf((q0 + q1) + (q2 + q3));
          if (lane == 0) sls[b] = logf(s);
        }
      }
      __syncthreads();
      for (int b = 0; b < NB; b++) {
#pragma unroll
        for (int k = 0; k < 5; k++) {
          sval[tid * 5 + k] = p.ptop_v[(tid * NB + b) * 5 + k];
          sidx[tid * 5 + k] = p.ptop_i[(tid * NB + b) * 5 + k];
        }
        __syncthreads();
        for (int n = 128; n >= 1; n >>= 1) {
          if (tid < n) {
            float av[5], bv[5], ov[5];
            int ai[5], bi2[5], oi[5];
#pragma unroll
            for (int k = 0; k < 5; k++) {
              av[k] = sval[tid * 5 + k]; ai[k] = sidx[tid * 5 + k];
              bv[k] = sval[(tid + n) * 5 + k]; bi2[k] = sidx[(tid + n) * 5 + k];
            }
            int i = 0, j = 0;
#pragma unroll
            for (int k = 0; k < 5; k++) {
              bool ta = (av[i] > bv[j]) || (av[i] == bv[j] && ai[i] < bi2[j]);
              if (ta) { ov[k] = av[i]; oi[k] = ai[i]; i++; }
              else { ov[k] = bv[j]; oi[k] = bi2[j]; j++; }
            }
#pragma unroll
            for (int k = 0; k < 5; k++) { sval[tid * 5 + k] = ov[k]; sidx[tid * 5 + k] = oi[k]; }
          }
          __syncthreads();
        }
        if (tid == 0) {
#pragma unroll
          for (int k = 0; k < 5; k++) { smv[b * 5 + k] = sval[k]; smi[b * 5 + k] = sidx[k]; }
        }
        __syncthreads();
      }
      if (tid == 0) {
        float cand[25]; int ctok[25];
        for (int b = 0; b < NB; b++) {
          float sb = p.scores[b], lb = sls[b];
#pragma unroll
          for (int k = 0; k < 5; k++) {
            cand[b * 5 + k] = sb + (smv[b * 5 + k] - lb);
            ctok[b * 5 + k] = smi[b * 5 + k];
          }
        }
        float s5[5]; int f5[5];
#pragma unroll
        for (int k = 0; k < 5; k++) { s5[k] = -INFINITY; f5[k] = 0x7fffffff; }
        for (int f = 0; f < 25; f++) {
          float v = cand[f];
          if (v > s5[4]) {
            int k = 4;
            while (k > 0 && v > s5[k - 1]) { s5[k] = s5[k - 1]; f5[k] = f5[k - 1]; k--; }
            s5[k] = v; f5[k] = f;
          }
        }
        for (int j2 = 0; j2 < 5; j2++) {
          int fl = f5[j2];
          p.pars[t * NB + j2] = fl / 5;
          p.toks[t * NB + j2] = ctok[fl];
          p.cur_tok[j2] = ctok[fl];
        }
        for (int j2 = 0; j2 < 5; j2++) p.scores[j2] = s5[j2];
        __threadfence();
        __hip_atomic_store(flag6, (unsigned)(t + 1), __ATOMIC_RELEASE, __HIP_MEMORY_SCOPE_AGENT);
      }
    }
  }

  // ========== F: backtrack and write output (seq as float, then score) ==========
  if (wg == 0 && tid == 0) {
    int best = 0;
    float bvv = p.scores[0];
    for (int j = 1; j < NB; j++)
      if (p.scores[j] > bvv) { bvv = p.scores[j]; best = j; }
    int beam = best;
    for (int tt = TO - 1; tt >= 0; tt--) {
      p.out[tt] = (float)p.toks[tt * NB + beam];
      beam = p.pars[tt * NB + beam];
    }
    p.out[TO] = bvv;
  }
}

extern "C" void kernel_launch(void* const* d_in, const int* in_sizes, int n_in,
                              void* d_out, int out_size, void* d_ws, size_t ws_size,
                              hipStream_t stream) {
  (void)in_sizes; (void)n_in; (void)out_size; (void)ws_size;
  Params p;
  p.seq  = (const int*)d_in[0];
  p.sosp = (const int*)d_in[3];
  p.emb  = (const float*)d_in[4];
  p.eWi  = (const float*)d_in[5];
  p.eWh  = (const float*)d_in[6];
  p.ebi  = (const float*)d_in[7];
  p.ebh  = (const float*)d_in[8];
  p.dWi  = (const float*)d_in[9];
  p.dWh  = (const float*)d_in[10];
  p.dbi  = (const float*)d_in[11];
  p.dbh  = (const float*)d_in[12];
  p.Wc   = (const float*)d_in[13];
  p.bc   = (const float*)d_in[14];
  p.Wout = (const float*)d_in[15];
  p.bout = (const float*)d_in[16];

  char* w = (char*)d_ws;
  size_t off = 0;
  auto alloc = [&](size_t words) -> char* {
    char* r = w + off;
    off += words * 4;
    off = (off + 255) & ~(size_t)255;
    return r;
  };
  p.bar     = (unsigned*)alloc(512);          // counters/flags (memset below)
  p.cur_tok = (int*)alloc(8);
  p.toks    = (int*)alloc(TO * NB);
  p.pars    = (int*)alloc(TO * NB);
  p.ptop_i  = (int*)alloc(NWG * NB * 5);
  p.gi0     = (float*)alloc((size_t)TI * G3);
  p.eout    = (float*)alloc((size_t)TI * HH);
  p.h0b     = (float*)alloc(2 * HH);
  p.h1b     = (float*)alloc(2 * HH);
  p.dch     = (float*)alloc(2 * 2 * NB * HH);
  p.cc      = (float*)alloc(NB * HH);
  p.ptop_v  = (float*)alloc(NWG * NB * 5);
  p.psum    = (float*)alloc(NWG * NB);
  p.scores  = (float*)alloc(8);
  p.out     = (float*)d_out;

  (void)hipMemsetAsync(d_ws, 0, 2048, stream);  // zero counters each call
  void* args[] = { &p };
  hipError_t err = hipLaunchCooperativeKernel((void*)bsd_kernel, dim3(NWG), dim3(NTHR),
                                              args, 0, stream);
  if (err != hipSuccess) {
    // Cooperative launch rejected (e.g. resource-based co-residency check).
    // 256 WGs x 256 thr at >=1 WG/CU on 256 CUs: all blocks resident in
    // practice; our barriers are custom counters, no cooperative-groups API.
    bsd_kernel<<<dim3(NWG), dim3(NTHR), 0, stream>>>(p);
  }
}

// Round 7
// 17260.646 us; speedup vs baseline: 2.8180x; 2.8180x over previous
//
#include <hip/hip_runtime.h>
#include <math.h>

// ---------------- problem dims ----------------
#define VV 32000
#define HH 512
#define G3 1536   // 3*HH
#define TI 128    // encoder length
#define TO 64    // max decode length
#define NB 5      // beam width
#define NEGF (-1000000000.0f)

// ---------------- grid config ----------------
#define NWG 256
#define NTHR 256
#define KGRU 64   // WGs running encoder recurrence + decoder GRU
#define KPA 40    // WGs running attention+Wc phase (8 per beam)

struct Params {
  const int* seq;
  const int* sosp;
  const float *emb, *eWi, *eWh, *ebi, *ebh;
  const float *dWi, *dWh, *dbi, *dbh;
  const float *Wc, *bc, *Wout, *bout;
  unsigned* bar;
  int *cur_tok, *toks, *pars, *ptop_i;
  float *gi0, *eout, *h0b, *h1b, *dch, *cc, *ptop_v, *psum, *scores;
  float* out;
};

// Relaxed agent-scope data movement: reaches the coherence point, never
// serves from a stale L1/L2 line, and emits NO cache-maintenance ops.
__device__ __forceinline__ float cldf(const float* p) {
  return __hip_atomic_load(p, __ATOMIC_RELAXED, __HIP_MEMORY_SCOPE_AGENT);
}
__device__ __forceinline__ void cstf(float* p, float v) {
  __hip_atomic_store(p, v, __ATOMIC_RELAXED, __HIP_MEMORY_SCOPE_AGENT);
}
__device__ __forceinline__ int cldi(const int* p) {
  return __hip_atomic_load(p, __ATOMIC_RELAXED, __HIP_MEMORY_SCOPE_AGENT);
}
__device__ __forceinline__ void csti(int* p, int v) {
  __hip_atomic_store(p, v, __ATOMIC_RELAXED, __HIP_MEMORY_SCOPE_AGENT);
}

// Arrival: __syncthreads() orders the WG's prior stores before thread 0's
// RELEASE fetch_add (one release per WG per sync hop).
__device__ __forceinline__ void arrive(unsigned* c) {
  __syncthreads();
  if (threadIdx.x == 0)
    __hip_atomic_fetch_add(c, 1u, __ATOMIC_RELEASE, __HIP_MEMORY_SCOPE_AGENT);
}
// Wait: RELAXED spin (cheap polls, no cache ops), then ONE acquire load so
// subsequent loads observe everything released before the counter reached v.
template <int SLP>
__device__ __forceinline__ void waitge(const unsigned* c, unsigned v) {
  if (threadIdx.x == 0) {
    while (__hip_atomic_load(c, __ATOMIC_RELAXED, __HIP_MEMORY_SCOPE_AGENT) < v)
      __builtin_amdgcn_s_sleep(SLP);
    (void)__hip_atomic_load(c, __ATOMIC_ACQUIRE, __HIP_MEMORY_SCOPE_AGENT);
  }
  __syncthreads();
}

__device__ __forceinline__ float wredf(float v) {
#pragma unroll
  for (int o = 32; o; o >>= 1) v += __shfl_xor(v, o, 64);
  return v;
}

// Decoder GRU layer over KGRU WGs, weights register-resident.
template <int LAYER>
__device__ void dec_gru_reg(const Params& p, float* sm, int t, int ib, int ob,
                            const float (&wd)[12][8]) {
  const int wg = blockIdx.x, tid = threadIdx.x;
  const int lane = tid & 63, wv = tid >> 6;
  float* sx = sm;                 // [NB][HH]
  float* sh = sm + NB * HH;       // [NB][HH]
  float* fres = sm + 2 * NB * HH; // [48][NB]

  int ct[NB], pr[NB];
#pragma unroll
  for (int b = 0; b < NB; b++) {
    ct[b] = (LAYER == 0) ? cldi(&p.cur_tok[b]) : 0;
    pr[b] = (t == 0) ? b : cldi(&p.pars[(t - 1) * NB + b]);
  }
  for (int i = tid; i < NB * HH; i += NTHR) {
    int b = i / HH, u = i - b * HH;
    float xv;
    if (LAYER == 0) xv = p.emb[(size_t)ct[b] * HH + u];               // read-only, cached
    else            xv = cldf(&p.dch[((size_t)(ob * 2 + 0) * NB + b) * HH + u]);
    sx[i] = xv;
    sh[i] = cldf(&p.dch[((size_t)(ib * 2 + LAYER) * NB + pr[b]) * HH + u]);
  }
  __syncthreads();
#pragma unroll
  for (int k = 0; k < 12; k++) {
    const int m_ = k % 6;                  // f%6 == k%6 since f = wv*12 + k
    const int f = wv * 12 + k;
    const float* vecb = (m_ >= 3) ? sh : sx;
    float a0 = 0.f, a1 = 0.f, a2 = 0.f, a3 = 0.f, a4 = 0.f;
#pragma unroll
    for (int j = 0; j < 8; j++) {
      float wj = wd[k][j];
      int o = j * 64 + lane;
      a0 += wj * vecb[0 * HH + o];
      a1 += wj * vecb[1 * HH + o];
      a2 += wj * vecb[2 * HH + o];
      a3 += wj * vecb[3 * HH + o];
      a4 += wj * vecb[4 * HH + o];
    }
    float r0 = wredf(a0), r1 = wredf(a1), r2 = wredf(a2), r3 = wredf(a3), r4 = wredf(a4);
    if (lane == 0) {
      fres[f * NB + 0] = r0; fres[f * NB + 1] = r1; fres[f * NB + 2] = r2;
      fres[f * NB + 3] = r3; fres[f * NB + 4] = r4;
    }
  }
  __syncthreads();
  if (tid < 8 * NB) {
    int ul = tid / NB, b = tid - ul * NB;
    int u = wg * 8 + ul;
    const float* bi = p.dbi + LAYER * G3;
    const float* bh = p.dbh + LAYER * G3;
    float ir = fres[(ul * 6 + 0) * NB + b] + bi[u];
    float iz = fres[(ul * 6 + 1) * NB + b] + bi[HH + u];
    float inn = fres[(ul * 6 + 2) * NB + b] + bi[2 * HH + u];
    float hr = fres[(ul * 6 + 3) * NB + b] + bh[u];
    float hz = fres[(ul * 6 + 4) * NB + b] + bh[HH + u];
    float hn = fres[(ul * 6 + 5) * NB + b] + bh[2 * HH + u];
    float hp = sh[b * HH + u];
    float r = 1.f / (1.f + expf(-(ir + hr)));
    float z = 1.f / (1.f + expf(-(iz + hz)));
    float n = tanhf(inn + r * hn);
    cstf(&p.dch[((size_t)(ob * 2 + LAYER) * NB + b) * HH + u], (1.f - z) * n + z * hp);
  }
}

__global__ void __launch_bounds__(NTHR, 1) bsd_kernel(Params p) {
  const int wg = blockIdx.x, tid = threadIdx.x;
  const int lane = tid & 63, wv = tid >> 6;
  __shared__ float sm[5504];

  unsigned* c_grid = p.bar + 0;
  unsigned* c_enc  = p.bar + 16;
  unsigned* c1     = p.bar + 32;
  unsigned* c2     = p.bar + 48;
  unsigned* c3     = p.bar + 64;
  unsigned* c5     = p.bar + 80;
  unsigned* flag6  = p.bar + 96;
  unsigned* fenc   = p.bar + 112;

  // ========== E0: gi0[t][row] = emb[seq[t]] . eWi0[row] + ebi0[row]; zero h ==========
  {
    if (wg == 0) {
      for (int i = tid; i < 2 * HH; i += NTHR) { cstf(&p.h0b[i], 0.f); cstf(&p.h1b[i], 0.f); }
    }
    for (int lr = wv; lr < 6; lr += 4) {
      int row = wg * 6 + lr;
      const float* W = p.eWi + (size_t)row * HH;
      float w0[8];
#pragma unroll
      for (int j = 0; j < 8; j++) w0[j] = W[j * 64 + lane];
      float bi = p.ebi[row];
      for (int t = 0; t < TI; t++) {
        const float* x = p.emb + (size_t)p.seq[t] * HH;
        float s = 0.f;
#pragma unroll
        for (int j = 0; j < 8; j++) s += w0[j] * x[j * 64 + lane];
        s = wredf(s);
        if (lane == 0) cstf(&p.gi0[(size_t)t * G3 + row], s + bi);
      }
    }
  }
  arrive(c_grid);
  waitge<2>(c_grid, NWG);

  // ========== E1: recurrence on KGRU WGs, register weights, 129 mini-barriers ==========
  if (wg < KGRU) {
    float wreg[24][8];  // L0 waves: rows [uu*3+g]; L1 waves: rows [uu*6+mg]
    if (wv < 2) {
#pragma unroll
      for (int uu = 0; uu < 4; uu++) {
        int u = wg * 8 + wv * 4 + uu;
#pragma unroll
        for (int g = 0; g < 3; g++) {
          const float* W = p.eWh + (size_t)(g * HH + u) * HH;
#pragma unroll
          for (int j = 0; j < 8; j++) wreg[uu * 3 + g][j] = W[j * 64 + lane];
        }
      }
    } else {
#pragma unroll
      for (int uu = 0; uu < 4; uu++) {
        int u = wg * 8 + (wv - 2) * 4 + uu;
#pragma unroll
        for (int g = 0; g < 3; g++) {
          const float* Wi1 = p.eWi + (size_t)G3 * HH + (size_t)(g * HH + u) * HH;
          const float* Wh1 = p.eWh + (size_t)G3 * HH + (size_t)(g * HH + u) * HH;
#pragma unroll
          for (int j = 0; j < 8; j++) {
            wreg[uu * 6 + g][j] = Wi1[j * 64 + lane];
            wreg[uu * 6 + 3 + g][j] = Wh1[j * 64 + lane];
          }
        }
      }
    }
    for (int T = 0; T <= TI; T++) {
      const int sIn = T & 1, sOut = sIn ^ 1;
      if (wv < 2) {
        if (T < TI) {
          float hv[8];
#pragma unroll
          for (int j = 0; j < 8; j++) hv[j] = cldf(&p.h0b[sIn * HH + j * 64 + lane]);
#pragma unroll
          for (int uu = 0; uu < 4; uu++) {
            int u = wg * 8 + wv * 4 + uu;
            float g[3];
#pragma unroll
            for (int gg = 0; gg < 3; gg++) {
              float s = 0.f;
#pragma unroll
              for (int j = 0; j < 8; j++) s += wreg[uu * 3 + gg][j] * hv[j];
              g[gg] = wredf(s);
            }
            if (lane == 0) {
              const float* gr = p.gi0 + (size_t)T * G3;
              float ir = cldf(&gr[u]), iz = cldf(&gr[HH + u]), inn = cldf(&gr[2 * HH + u]);
              float hr = g[0] + p.ebh[u], hz = g[1] + p.ebh[HH + u], hn = g[2] + p.ebh[2 * HH + u];
              float r = 1.f / (1.f + expf(-(ir + hr)));
              float z = 1.f / (1.f + expf(-(iz + hz)));
              float n = tanhf(inn + r * hn);
              float hp = cldf(&p.h0b[sIn * HH + u]);
              cstf(&p.h0b[sOut * HH + u], (1.f - z) * n + z * hp);
            }
          }
        }
      } else {
        if (T >= 1) {
          float xv[8], hv[8];
#pragma unroll
          for (int j = 0; j < 8; j++) {
            xv[j] = cldf(&p.h0b[sIn * HH + j * 64 + lane]);
            hv[j] = cldf(&p.h1b[sOut * HH + j * 64 + lane]);
          }
#pragma unroll
          for (int uu = 0; uu < 4; uu++) {
            int u = wg * 8 + (wv - 2) * 4 + uu;
            float gi[3], gh[3];
#pragma unroll
            for (int gg = 0; gg < 3; gg++) {
              float si = 0.f, s2 = 0.f;
#pragma unroll
              for (int j = 0; j < 8; j++) {
                si += wreg[uu * 6 + gg][j] * xv[j];
                s2 += wreg[uu * 6 + 3 + gg][j] * hv[j];
              }
              gi[gg] = wredf(si);
              gh[gg] = wredf(s2);
            }
            if (lane == 0) {
              const float* bi = p.ebi + G3;
              const float* bh = p.ebh + G3;
              float ir = gi[0] + bi[u], iz = gi[1] + bi[HH + u], inn = gi[2] + bi[2 * HH + u];
              float hr = gh[0] + bh[u], hz = gh[1] + bh[HH + u], hn = gh[2] + bh[2 * HH + u];
              float r = 1.f / (1.f + expf(-(ir + hr)));
              float z = 1.f / (1.f + expf(-(iz + hz)));
              float n = tanhf(inn + r * hn);
              float hp = cldf(&p.h1b[sOut * HH + u]);
              float hnew = (1.f - z) * n + z * hp;
              cstf(&p.h1b[sIn * HH + u], hnew);
              cstf(&p.eout[(size_t)(T - 1) * HH + u], hnew);
            }
          }
        }
      }
      arrive(c_enc);
      waitge<2>(c_enc, (unsigned)(KGRU * (T + 1)));
    }
    if (wg == 0 && tid == 0)
      __hip_atomic_store(fenc, 1u, __ATOMIC_RELEASE, __HIP_MEMORY_SCOPE_AGENT);
  } else {
    waitge<8>(fenc, 1u);
  }

  // ---- load decoder GRU weights into registers (KGRU WGs), both layers ----
  float wdec[2][12][8];
  if (wg < KGRU) {
#pragma unroll
    for (int k = 0; k < 12; k++) {
      const int f = wv * 12 + k;
      const int ul = f / 6, m_ = f % 6;
      const int u = wg * 8 + ul;
      const float* W0 = (m_ < 3 ? p.dWi : p.dWh) + (size_t)((m_ % 3) * HH + u) * HH;
      const float* W1 = (m_ < 3 ? p.dWi : p.dWh) + (size_t)G3 * HH + (size_t)((m_ % 3) * HH + u) * HH;
#pragma unroll
      for (int j = 0; j < 8; j++) { wdec[0][k][j] = W0[j * 64 + lane]; wdec[1][k][j] = W1[j * 64 + lane]; }
    }
  }

  // ========== D0: broadcast enc_hidden to beams, init tokens/scores ==========
  {
    for (int i = tid + wg * NTHR; i < 2 * NB * HH; i += NWG * NTHR) {
      int l = i / (NB * HH);
      int rem = i - l * (NB * HH);
      int u = rem % HH;
      float hv = (l == 0) ? cldf(&p.h0b[u]) : cldf(&p.h1b[u]);
      cstf(&p.dch[(size_t)l * NB * HH + rem], hv);
    }
    if (wg == 0 && tid < NB) {
      csti(&p.cur_tok[tid], p.sosp[0]);
      cstf(&p.scores[tid], (tid == 0) ? 0.f : NEGF);
    }
  }
  arrive(c_grid);
  waitge<2>(c_grid, 2 * NWG);

  // ========== decoder: 64 steps ==========
  for (int t = 0; t < TO; t++) {
    const int ib = t & 1, ob = ib ^ 1;

    waitge<2>(flag6, (unsigned)t);  // step-t inputs (cur_tok/pars/scores) ready

    if (wg < KGRU) {
      dec_gru_reg<0>(p, sm, t, ib, ob, wdec[0]);
      arrive(c1);
      waitge<2>(c1, (unsigned)(KGRU * (t + 1)));
      dec_gru_reg<1>(p, sm, t, ib, ob, wdec[1]);
      arrive(c2);
      waitge<2>(c2, (unsigned)(KGRU * (t + 1)));
    }

    // ---- PA: attention + ctx + Wc + tanh (40 WGs, 8 per beam) ----
    if (wg < KPA) {
      const int b = wg / 8, q = wg % 8;
      float* srnn = sm;           // 512
      float* sp = sm + HH;        // 128 scores -> probs
      float* sctx = sm + HH + TI; // 512
      for (int i = tid; i < HH; i += NTHR)
        srnn[i] = cldf(&p.dch[((size_t)(ob * 2 + 1) * NB + b) * HH + i]);
      __syncthreads();
      for (int j = wv; j < TI; j += 4) {
        const float* E = p.eout + (size_t)j * HH;
        float s = 0.f;
#pragma unroll
        for (int k = 0; k < 8; k++) s += srnn[k * 64 + lane] * cldf(&E[k * 64 + lane]);
        s = wredf(s);
        if (lane == 0) sp[j] = s;
      }
      __syncthreads();
      if (wv == 0) {
        float v0 = sp[lane], v1 = sp[64 + lane];
        float mx = fmaxf(v0, v1);
#pragma unroll
        for (int o = 32; o; o >>= 1) mx = fmaxf(mx, __shfl_xor(mx, o, 64));
        float e0 = expf(v0 - mx), e1 = expf(v1 - mx);
        float ss = wredf(e0 + e1);
        sp[lane] = e0 / ss;
        sp[64 + lane] = e1 / ss;
      }
      __syncthreads();
      for (int u = tid; u < HH; u += NTHR) {
        float s = 0.f;
        for (int j = 0; j < TI; j++) s += sp[j] * cldf(&p.eout[(size_t)j * HH + u]);
        sctx[u] = s;
      }
      __syncthreads();
      for (int k = wv; k < 64; k += 4) {
        int u = q * 64 + k;
        const float* W = p.Wc + (size_t)u * (2 * HH);
        float s0 = 0.f, s1 = 0.f;
#pragma unroll
        for (int j = 0; j < 8; j++) {
          int o = j * 64 + lane;
          s0 += W[o] * srnn[o];
          s1 += W[HH + o] * sctx[o];
        }
        float r0 = wredf(s0), r1 = wredf(s1);
        if (lane == 0) cstf(&p.cc[b * HH + u], tanhf(r0 + r1 + p.bc[u]));
      }
      arrive(c3);
    }
    waitge<2>(c3, (unsigned)(KPA * (t + 1)));

    // ---- P5: logits chunk (125 rows/WG) + per-beam partial top5 + exp-sum ----
    {
      float* scc = sm;            // [NB][HH]
      float* slg = sm + NB * HH;  // [NB][125]
      for (int i = tid; i < NB * HH; i += NTHR) scc[i] = cldf(&p.cc[i]);
      __syncthreads();
      const int vbase = wg * 125;
      for (int r = wv; r < 125; r += 4) {
        int v = vbase + r;
        const float* W = p.Wout + (size_t)v * HH;
        float w0[8];
#pragma unroll
        for (int j = 0; j < 8; j++) w0[j] = W[j * 64 + lane];
        float a0 = 0.f, a1 = 0.f, a2 = 0.f, a3 = 0.f, a4 = 0.f;
#pragma unroll
        for (int j = 0; j < 8; j++) {
          float wj = w0[j];
          int o = j * 64 + lane;
          a0 += wj * scc[0 * HH + o];
          a1 += wj * scc[1 * HH + o];
          a2 += wj * scc[2 * HH + o];
          a3 += wj * scc[3 * HH + o];
          a4 += wj * scc[4 * HH + o];
        }
        float r0 = wredf(a0), r1 = wredf(a1), r2 = wredf(a2), r3 = wredf(a3), r4 = wredf(a4);
        if (lane == 0) {
          float bo = p.bout[v];
          slg[0 * 125 + r] = r0 + bo;
          slg[1 * 125 + r] = r1 + bo;
          slg[2 * 125 + r] = r2 + bo;
          slg[3 * 125 + r] = r3 + bo;
          slg[4 * 125 + r] = r4 + bo;
        }
      }
      __syncthreads();
      if (wv == 0) {
        for (int b = 0; b < NB; b++) {
          float s0 = (lane < 125) ? expf(slg[b * 125 + lane]) : 0.f;
          float s1 = (lane + 64 < 125) ? expf(slg[b * 125 + lane + 64]) : 0.f;
          float ss = wredf(s0 + s1);
          if (lane == 0) cstf(&p.psum[wg * NB + b], ss);
        }
      } else if (wv == 1 && lane < NB) {
        int b = lane;
        float bv[5]; int bidx[5];
#pragma unroll
        for (int k = 0; k < 5; k++) { bv[k] = -INFINITY; bidx[k] = 0x7fffffff; }
        for (int r = 0; r < 125; r++) {
          float v = slg[b * 125 + r];
          if (v > bv[4]) {  // strict >: equal values keep earlier (lower) index
            int k = 4;
            while (k > 0 && v > bv[k - 1]) { bv[k] = bv[k - 1]; bidx[k] = bidx[k - 1]; k--; }
            bv[k] = v; bidx[k] = vbase + r;
          }
        }
#pragma unroll
        for (int k = 0; k < 5; k++) {
          cstf(&p.ptop_v[(wg * NB + b) * 5 + k], bv[k]);
          csti(&p.ptop_i[(wg * NB + b) * 5 + k], bidx[k]);
        }
      }
    }
    arrive(c5);

    // ---- P6: merge (WG 0): lse, global top5/beam, 25-cand top5, bookkeeping ----
    if (wg == 0) {
      waitge<2>(c5, (unsigned)(NWG * (t + 1)));
      float* sval = sm;                  // [256][5]
      int* sidx = (int*)(sm + 1280);     // [256][5]
      float* sls = sm + 2560;            // [5]
      float* smv = sm + 2576;            // [5][5]
      int* smi = (int*)(sm + 2608);      // [5][5]
      if (wv == 0) {
        for (int b = 0; b < NB; b++) {
          float q0 = cldf(&p.psum[(lane + 0) * NB + b]);
          float q1 = cldf(&p.psum[(lane + 64) * NB + b]);
          float q2 = cldf(&p.psum[(lane + 128) * NB + b]);
          float q3 = cldf(&p.psum[(lane + 192) * NB + b]);
          float s = wredf((q0 + q1) + (q2 + q3));
          if (lane == 0) sls[b] = logf(s);
        }
      }
      __syncthreads();
      for (int b = 0; b < NB; b++) {
#pragma unroll
        for (int k = 0; k < 5; k++) {
          sval[tid * 5 + k] = cldf(&p.ptop_v[(tid * NB + b) * 5 + k]);
          sidx[tid * 5 + k] = cldi(&p.ptop_i[(tid * NB + b) * 5 + k]);
        }
        __syncthreads();
        for (int n = 128; n >= 1; n >>= 1) {
          if (tid < n) {
            float av[5], bv[5], ov[5];
            int ai[5], bi2[5], oi[5];
#pragma unroll
            for (int k = 0; k < 5; k++) {
              av[k] = sval[tid * 5 + k]; ai[k] = sidx[tid * 5 + k];
              bv[k] = sval[(tid + n) * 5 + k]; bi2[k] = sidx[(tid + n) * 5 + k];
            }
            int i = 0, j = 0;
#pragma unroll
            for (int k = 0; k < 5; k++) {
              bool ta = (av[i] > bv[j]) || (av[i] == bv[j] && ai[i] < bi2[j]);
              if (ta) { ov[k] = av[i]; oi[k] = ai[i]; i++; }
              else { ov[k] = bv[j]; oi[k] = bi2[j]; j++; }
            }
#pragma unroll
            for (int k = 0; k < 5; k++) { sval[tid * 5 + k] = ov[k]; sidx[tid * 5 + k] = oi[k]; }
          }
          __syncthreads();
        }
        if (tid == 0) {
#pragma unroll
          for (int k = 0; k < 5; k++) { smv[b * 5 + k] = sval[k]; smi[b * 5 + k] = sidx[k]; }
        }
        __syncthreads();
      }
      if (tid == 0) {
        float cand[25]; int ctok[25];
        for (int b = 0; b < NB; b++) {
          float sb = cldf(&p.scores[b]), lb = sls[b];
#pragma unroll
          for (int k = 0; k < 5; k++) {
            cand[b * 5 + k] = sb + (smv[b * 5 + k] - lb);
            ctok[b * 5 + k] = smi[b * 5 + k];
          }
        }
        float s5[5]; int f5[5];
#pragma unroll
        for (int k = 0; k < 5; k++) { s5[k] = -INFINITY; f5[k] = 0x7fffffff; }
        for (int f = 0; f < 25; f++) {
          float v = cand[f];
          if (v > s5[4]) {
            int k = 4;
            while (k > 0 && v > s5[k - 1]) { s5[k] = s5[k - 1]; f5[k] = f5[k - 1]; k--; }
            s5[k] = v; f5[k] = f;
          }
        }
        for (int j2 = 0; j2 < 5; j2++) {
          int fl = f5[j2];
          csti(&p.pars[t * NB + j2], fl / 5);
          csti(&p.toks[t * NB + j2], ctok[fl]);
          csti(&p.cur_tok[j2], ctok[fl]);
        }
        for (int j2 = 0; j2 < 5; j2++) cstf(&p.scores[j2], s5[j2]);
        __hip_atomic_store(flag6, (unsigned)(t + 1), __ATOMIC_RELEASE, __HIP_MEMORY_SCOPE_AGENT);
      }
    }
  }

  // ========== F: backtrack and write output (seq as float, then score) ==========
  if (wg == 0 && tid == 0) {
    int best = 0;
    float bvv = cldf(&p.scores[0]);
    for (int j = 1; j < NB; j++) {
      float sj = cldf(&p.scores[j]);
      if (sj > bvv) { bvv = sj; best = j; }
    }
    int beam = best;
    for (int tt = TO - 1; tt >= 0; tt--) {
      p.out[tt] = (float)cldi(&p.toks[tt * NB + beam]);
      beam = cldi(&p.pars[tt * NB + beam]);
    }
    p.out[TO] = bvv;
  }
}

extern "C" void kernel_launch(void* const* d_in, const int* in_sizes, int n_in,
                              void* d_out, int out_size, void* d_ws, size_t ws_size,
                              hipStream_t stream) {
  (void)in_sizes; (void)n_in; (void)out_size; (void)ws_size;
  Params p;
  p.seq  = (const int*)d_in[0];
  p.sosp = (const int*)d_in[3];
  p.emb  = (const float*)d_in[4];
  p.eWi  = (const float*)d_in[5];
  p.eWh  = (const float*)d_in[6];
  p.ebi  = (const float*)d_in[7];
  p.ebh  = (const float*)d_in[8];
  p.dWi  = (const float*)d_in[9];
  p.dWh  = (const float*)d_in[10];
  p.dbi  = (const float*)d_in[11];
  p.dbh  = (const float*)d_in[12];
  p.Wc   = (const float*)d_in[13];
  p.bc   = (const float*)d_in[14];
  p.Wout = (const float*)d_in[15];
  p.bout = (const float*)d_in[16];

  char* w = (char*)d_ws;
  size_t off = 0;
  auto alloc = [&](size_t words) -> char* {
    char* r = w + off;
    off += words * 4;
    off = (off + 255) & ~(size_t)255;
    return r;
  };
  p.bar     = (unsigned*)alloc(512);          // counters/flags (memset below)
  p.cur_tok = (int*)alloc(8);
  p.toks    = (int*)alloc(TO * NB);
  p.pars    = (int*)alloc(TO * NB);
  p.ptop_i  = (int*)alloc(NWG * NB * 5);
  p.gi0     = (float*)alloc((size_t)TI * G3);
  p.eout    = (float*)alloc((size_t)TI * HH);
  p.h0b     = (float*)alloc(2 * HH);
  p.h1b     = (float*)alloc(2 * HH);
  p.dch     = (float*)alloc(2 * 2 * NB * HH);
  p.cc      = (float*)alloc(NB * HH);
  p.ptop_v  = (float*)alloc(NWG * NB * 5);
  p.psum    = (float*)alloc(NWG * NB);
  p.scores  = (float*)alloc(8);
  p.out     = (float*)d_out;

  (void)hipMemsetAsync(d_ws, 0, 2048, stream);  // zero counters each call
  // Plain launch (round 6 proved it passes): 256 WGs x 256 thr at 1 WG/CU on
  // 256 CUs -> all blocks co-resident. hipLaunchCooperativeKernel silently
  // rejects this kernel at VGPR=256 (rounds 4/5 failure mode) - do not use it.
  bsd_kernel<<<dim3(NWG), dim3(NTHR), 0, stream>>>(p);
}

// Round 8
// 16548.640 us; speedup vs baseline: 2.9392x; 1.0430x over previous
//
#include <hip/hip_runtime.h>
#include <math.h>

// ---------------- problem dims ----------------
#define VV 32000
#define HH 512
#define G3 1536   // 3*HH
#define TI 128    // encoder length
#define TO 64     // max decode length
#define NB 5      // beam width
#define NEGF (-1000000000.0f)

// ---------------- grid config ----------------
#define NWG 256
#define NTHR 256
#define KGRU 64   // WGs running encoder recurrence + decoder GRU
#define KPA 40    // WGs running attention+Wc phase (8 per beam)
#define LSTR 32   // words per counter line (128B) - one atomic line per 8-way split

struct Params {
  const int* seq;
  const int* sosp;
  const float *emb, *eWi, *eWh, *ebi, *ebh;
  const float *dWi, *dWh, *dbi, *dbh;
  const float *Wc, *bc, *Wout, *bout;
  unsigned* bar;
  int *cur_tok, *toks, *pars, *ptop_i;
  float *gi0, *eout, *h0b, *h1b, *dch, *cc, *ptop_v, *psum, *scores;
  float* out;
};

// Relaxed agent-scope data movement: reaches the coherence point (bypasses
// stale L1/L2) and emits NO cache-maintenance ops. All cross-WG data uses
// these, which is why the barriers below need no release/acquire cache ops:
// __syncthreads() drains vmcnt(0) per wave => stores are at the coherence
// point before the counter RMW is issued.
__device__ __forceinline__ float cldf(const float* p) {
  return __hip_atomic_load(p, __ATOMIC_RELAXED, __HIP_MEMORY_SCOPE_AGENT);
}
__device__ __forceinline__ void cstf(float* p, float v) {
  __hip_atomic_store(p, v, __ATOMIC_RELAXED, __HIP_MEMORY_SCOPE_AGENT);
}
__device__ __forceinline__ int cldi(const int* p) {
  return __hip_atomic_load(p, __ATOMIC_RELAXED, __HIP_MEMORY_SCOPE_AGENT);
}
__device__ __forceinline__ void csti(int* p, int v) {
  __hip_atomic_store(p, v, __ATOMIC_RELAXED, __HIP_MEMORY_SCOPE_AGENT);
}
__device__ __forceinline__ unsigned rldu(const unsigned* p) {
  return __hip_atomic_load(p, __ATOMIC_RELAXED, __HIP_MEMORY_SCOPE_AGENT);
}

// arrivals split over 8 cache lines (myline in [0,8)) to de-serialize RMWs
__device__ __forceinline__ void bar_arrive(unsigned* lines, int myline) {
  __syncthreads();
  if (threadIdx.x == 0)
    __hip_atomic_fetch_add(lines + myline * LSTR, 1u,
                           __ATOMIC_RELAXED, __HIP_MEMORY_SCOPE_AGENT);
}
// wave0 lanes 0..7 poll the 8 lines in one round trip
template <int SLP>
__device__ __forceinline__ void bar_wait8(const unsigned* lines, unsigned tgt) {
  if (threadIdx.x < 64) {
    for (;;) {
      unsigned v = tgt;
      if (threadIdx.x < 8) v = rldu(lines + threadIdx.x * LSTR);
      if (__all(v >= tgt)) break;
      __builtin_amdgcn_s_sleep(SLP);
    }
  }
  __syncthreads();
}
// single-writer broadcast flag
template <int SLP>
__device__ __forceinline__ void flag_wait(const unsigned* f, unsigned tgt) {
  if (threadIdx.x == 0) {
    while (rldu(f) < tgt) __builtin_amdgcn_s_sleep(SLP);
  }
  __syncthreads();
}
__device__ __forceinline__ void flag_store(unsigned* f, unsigned v) {
  asm volatile("s_waitcnt vmcnt(0)" ::: "memory");  // own stores at coherence point
  __hip_atomic_store(f, v, __ATOMIC_RELAXED, __HIP_MEMORY_SCOPE_AGENT);
}

__device__ __forceinline__ float wredf(float v) {
#pragma unroll
  for (int o = 32; o; o >>= 1) v += __shfl_xor(v, o, 64);
  return v;
}

// Decoder GRU layer over KGRU WGs, weights register-resident.
template <int LAYER>
__device__ void dec_gru_reg(const Params& p, float* sm, int t, int ib, int ob,
                            const float (&wd)[12][8]) {
  const int wg = blockIdx.x, tid = threadIdx.x;
  const int lane = tid & 63, wv = tid >> 6;
  float* sx = sm;                 // [NB][HH]
  float* sh = sm + NB * HH;       // [NB][HH]
  float* fres = sm + 2 * NB * HH; // [48][NB]

  int ct[NB], pr[NB];
#pragma unroll
  for (int b = 0; b < NB; b++) {
    ct[b] = (LAYER == 0) ? cldi(&p.cur_tok[b]) : 0;
    pr[b] = (t == 0) ? b : cldi(&p.pars[(t - 1) * NB + b]);
  }
  for (int i = tid; i < NB * HH; i += NTHR) {
    int b = i / HH, u = i - b * HH;
    float xv;
    if (LAYER == 0) xv = p.emb[(size_t)ct[b] * HH + u];               // read-only, cached
    else            xv = cldf(&p.dch[((size_t)(ob * 2 + 0) * NB + b) * HH + u]);
    sx[i] = xv;
    sh[i] = cldf(&p.dch[((size_t)(ib * 2 + LAYER) * NB + pr[b]) * HH + u]);
  }
  __syncthreads();
#pragma unroll
  for (int k = 0; k < 12; k++) {
    const int m_ = k % 6;                  // f%6 == k%6 since f = wv*12 + k
    const int f = wv * 12 + k;
    const float* vecb = (m_ >= 3) ? sh : sx;
    float a0 = 0.f, a1 = 0.f, a2 = 0.f, a3 = 0.f, a4 = 0.f;
#pragma unroll
    for (int j = 0; j < 8; j++) {
      float wj = wd[k][j];
      int o = j * 64 + lane;
      a0 += wj * vecb[0 * HH + o];
      a1 += wj * vecb[1 * HH + o];
      a2 += wj * vecb[2 * HH + o];
      a3 += wj * vecb[3 * HH + o];
      a4 += wj * vecb[4 * HH + o];
    }
    float r0 = wredf(a0), r1 = wredf(a1), r2 = wredf(a2), r3 = wredf(a3), r4 = wredf(a4);
    if (lane == 0) {
      fres[f * NB + 0] = r0; fres[f * NB + 1] = r1; fres[f * NB + 2] = r2;
      fres[f * NB + 3] = r3; fres[f * NB + 4] = r4;
    }
  }
  __syncthreads();
  if (tid < 8 * NB) {
    int ul = tid / NB, b = tid - ul * NB;
    int u = wg * 8 + ul;
    const float* bi = p.dbi + LAYER * G3;
    const float* bh = p.dbh + LAYER * G3;
    float ir = fres[(ul * 6 + 0) * NB + b] + bi[u];
    float iz = fres[(ul * 6 + 1) * NB + b] + bi[HH + u];
    float inn = fres[(ul * 6 + 2) * NB + b] + bi[2 * HH + u];
    float hr = fres[(ul * 6 + 3) * NB + b] + bh[u];
    float hz = fres[(ul * 6 + 4) * NB + b] + bh[HH + u];
    float hn = fres[(ul * 6 + 5) * NB + b] + bh[2 * HH + u];
    float hp = sh[b * HH + u];
    float r = 1.f / (1.f + expf(-(ir + hr)));
    float z = 1.f / (1.f + expf(-(iz + hz)));
    float n = tanhf(inn + r * hn);
    cstf(&p.dch[((size_t)(ob * 2 + LAYER) * NB + b) * HH + u], (1.f - z) * n + z * hp);
  }
}

__global__ void __launch_bounds__(NTHR, 1) bsd_kernel(Params p) {
  const int wg = blockIdx.x, tid = threadIdx.x;
  const int lane = tid & 63, wv = tid >> 6;
  __shared__ float sm[5504];

  unsigned* c1    = p.bar + 0 * LSTR;   // 8 lines each
  unsigned* c2    = p.bar + 8 * LSTR;
  unsigned* c3    = p.bar + 16 * LSTR;
  unsigned* c5    = p.bar + 24 * LSTR;
  unsigned* ce    = p.bar + 32 * LSTR;
  unsigned* cg    = p.bar + 40 * LSTR;
  unsigned* flag6 = p.bar + 48 * LSTR;  // single-writer flags, own lines
  unsigned* fenc  = p.bar + 49 * LSTR;
  unsigned* f3    = p.bar + 50 * LSTR;

  // ========== E0: gi0[t][row] = emb[seq[t]] . eWi0[row] + ebi0[row]; zero h ==========
  {
    if (wg == 0) {
      for (int i = tid; i < 2 * HH; i += NTHR) { cstf(&p.h0b[i], 0.f); cstf(&p.h1b[i], 0.f); }
    }
    for (int lr = wv; lr < 6; lr += 4) {
      int row = wg * 6 + lr;
      const float* W = p.eWi + (size_t)row * HH;
      float w0[8];
#pragma unroll
      for (int j = 0; j < 8; j++) w0[j] = W[j * 64 + lane];
      float bi = p.ebi[row];
      for (int t = 0; t < TI; t++) {
        const float* x = p.emb + (size_t)p.seq[t] * HH;
        float s = 0.f;
#pragma unroll
        for (int j = 0; j < 8; j++) s += w0[j] * x[j * 64 + lane];
        s = wredf(s);
        if (lane == 0) cstf(&p.gi0[(size_t)t * G3 + row], s + bi);
      }
    }
  }
  bar_arrive(cg, wg >> 5);
  bar_wait8<2>(cg, 32u);

  // ========== E1: recurrence on KGRU WGs, register weights, 129 mini-barriers ==========
  if (wg < KGRU) {
    float wreg[24][8];  // L0 waves: rows [uu*3+g]; L1 waves: rows [uu*6+mg]
    if (wv < 2) {
#pragma unroll
      for (int uu = 0; uu < 4; uu++) {
        int u = wg * 8 + wv * 4 + uu;
#pragma unroll
        for (int g = 0; g < 3; g++) {
          const float* W = p.eWh + (size_t)(g * HH + u) * HH;
#pragma unroll
          for (int j = 0; j < 8; j++) wreg[uu * 3 + g][j] = W[j * 64 + lane];
        }
      }
    } else {
#pragma unroll
      for (int uu = 0; uu < 4; uu++) {
        int u = wg * 8 + (wv - 2) * 4 + uu;
#pragma unroll
        for (int g = 0; g < 3; g++) {
          const float* Wi1 = p.eWi + (size_t)G3 * HH + (size_t)(g * HH + u) * HH;
          const float* Wh1 = p.eWh + (size_t)G3 * HH + (size_t)(g * HH + u) * HH;
#pragma unroll
          for (int j = 0; j < 8; j++) {
            wreg[uu * 6 + g][j] = Wi1[j * 64 + lane];
            wreg[uu * 6 + 3 + g][j] = Wh1[j * 64 + lane];
          }
        }
      }
    }
    for (int T = 0; T <= TI; T++) {
      const int sIn = T & 1, sOut = sIn ^ 1;
      if (wv < 2) {
        if (T < TI) {
          float hv[8];
#pragma unroll
          for (int j = 0; j < 8; j++) hv[j] = cldf(&p.h0b[sIn * HH + j * 64 + lane]);
#pragma unroll
          for (int uu = 0; uu < 4; uu++) {
            int u = wg * 8 + wv * 4 + uu;
            float g[3];
#pragma unroll
            for (int gg = 0; gg < 3; gg++) {
              float s = 0.f;
#pragma unroll
              for (int j = 0; j < 8; j++) s += wreg[uu * 3 + gg][j] * hv[j];
              g[gg] = wredf(s);
            }
            if (lane == 0) {
              const float* gr = p.gi0 + (size_t)T * G3;
              float ir = cldf(&gr[u]), iz = cldf(&gr[HH + u]), inn = cldf(&gr[2 * HH + u]);
              float hr = g[0] + p.ebh[u], hz = g[1] + p.ebh[HH + u], hn = g[2] + p.ebh[2 * HH + u];
              float r = 1.f / (1.f + expf(-(ir + hr)));
              float z = 1.f / (1.f + expf(-(iz + hz)));
              float n = tanhf(inn + r * hn);
              float hp = cldf(&p.h0b[sIn * HH + u]);
              cstf(&p.h0b[sOut * HH + u], (1.f - z) * n + z * hp);
            }
          }
        }
      } else {
        if (T >= 1) {
          float xv[8], hv[8];
#pragma unroll
          for (int j = 0; j < 8; j++) {
            xv[j] = cldf(&p.h0b[sIn * HH + j * 64 + lane]);
            hv[j] = cldf(&p.h1b[sOut * HH + j * 64 + lane]);
          }
#pragma unroll
          for (int uu = 0; uu < 4; uu++) {
            int u = wg * 8 + (wv - 2) * 4 + uu;
            float gi[3], gh[3];
#pragma unroll
            for (int gg = 0; gg < 3; gg++) {
              float si = 0.f, s2 = 0.f;
#pragma unroll
              for (int j = 0; j < 8; j++) {
                si += wreg[uu * 6 + gg][j] * xv[j];
                s2 += wreg[uu * 6 + 3 + gg][j] * hv[j];
              }
              gi[gg] = wredf(si);
              gh[gg] = wredf(s2);
            }
            if (lane == 0) {
              const float* bi = p.ebi + G3;
              const float* bh = p.ebh + G3;
              float ir = gi[0] + bi[u], iz = gi[1] + bi[HH + u], inn = gi[2] + bi[2 * HH + u];
              float hr = gh[0] + bh[u], hz = gh[1] + bh[HH + u], hn = gh[2] + bh[2 * HH + u];
              float r = 1.f / (1.f + expf(-(ir + hr)));
              float z = 1.f / (1.f + expf(-(iz + hz)));
              float n = tanhf(inn + r * hn);
              float hp = cldf(&p.h1b[sOut * HH + u]);
              float hnew = (1.f - z) * n + z * hp;
              cstf(&p.h1b[sIn * HH + u], hnew);
              cstf(&p.eout[(size_t)(T - 1) * HH + u], hnew);
            }
          }
        }
      }
      bar_arrive(ce, wg & 7);
      bar_wait8<1>(ce, (unsigned)(8 * (T + 1)));
    }
    if (wg == 0 && tid == 0) flag_store(fenc, 1u);
  } else {
    flag_wait<8>(fenc, 1u);
  }

  // ---- load decoder GRU weights into registers (KGRU WGs), both layers ----
  float wdec[2][12][8];
  if (wg < KGRU) {
#pragma unroll
    for (int k = 0; k < 12; k++) {
      const int f = wv * 12 + k;
      const int ul = f / 6, m_ = f % 6;
      const int u = wg * 8 + ul;
      const float* W0 = (m_ < 3 ? p.dWi : p.dWh) + (size_t)((m_ % 3) * HH + u) * HH;
      const float* W1 = (m_ < 3 ? p.dWi : p.dWh) + (size_t)G3 * HH + (size_t)((m_ % 3) * HH + u) * HH;
#pragma unroll
      for (int j = 0; j < 8; j++) { wdec[0][k][j] = W0[j * 64 + lane]; wdec[1][k][j] = W1[j * 64 + lane]; }
    }
  }

  // ========== D0: broadcast enc_hidden to beams, init tokens/scores ==========
  {
    for (int i = tid + wg * NTHR; i < 2 * NB * HH; i += NWG * NTHR) {
      int l = i / (NB * HH);
      int rem = i - l * (NB * HH);
      int u = rem % HH;
      float hv = (l == 0) ? cldf(&p.h0b[u]) : cldf(&p.h1b[u]);
      cstf(&p.dch[(size_t)l * NB * HH + rem], hv);
    }
    if (wg == 0 && tid < NB) {
      csti(&p.cur_tok[tid], p.sosp[0]);
      cstf(&p.scores[tid], (tid == 0) ? 0.f : NEGF);
    }
  }
  bar_arrive(cg, wg >> 5);
  bar_wait8<2>(cg, 64u);

  // ========== decoder: 64 steps ==========
  for (int t = 0; t < TO; t++) {
    const int ib = t & 1, ob = ib ^ 1;

    flag_wait<4>(flag6, (unsigned)t);  // step-t inputs ready (t=0 trivially)

    if (wg < KGRU) {
      dec_gru_reg<0>(p, sm, t, ib, ob, wdec[0]);
      bar_arrive(c1, wg & 7);
      bar_wait8<1>(c1, (unsigned)(8 * (t + 1)));
      dec_gru_reg<1>(p, sm, t, ib, ob, wdec[1]);
      bar_arrive(c2, wg & 7);
    }

    // ---- PA: attention + ctx + Wc + tanh (40 WGs, 8 per beam) ----
    if (wg < KPA) {
      bar_wait8<1>(c2, (unsigned)(8 * (t + 1)));
      const int b = wg / 8, q = wg % 8;
      float* srnn = sm;            // 512
      float* sp = sm + 512;        // 128
      float* cpart = sm + 640;     // [4][512]
      float* sctx = sm + 2688;     // 512
      for (int i = tid; i < HH; i += NTHR)
        srnn[i] = cldf(&p.dch[((size_t)(ob * 2 + 1) * NB + b) * HH + i]);
      __syncthreads();
      for (int j = wv; j < TI; j += 4) {
        const float* E = p.eout + (size_t)j * HH;
        float s = 0.f;
#pragma unroll
        for (int k2 = 0; k2 < 8; k2++) s += srnn[k2 * 64 + lane] * cldf(&E[k2 * 64 + lane]);
        s = wredf(s);
        if (lane == 0) sp[j] = s;
      }
      __syncthreads();
      if (wv == 0) {
        float v0 = sp[lane], v1 = sp[64 + lane];
        float mx = fmaxf(v0, v1);
#pragma unroll
        for (int o = 32; o; o >>= 1) mx = fmaxf(mx, __shfl_xor(mx, o, 64));
        float e0 = expf(v0 - mx), e1 = expf(v1 - mx);
        float ss = wredf(e0 + e1);
        sp[lane] = e0 / ss;
        sp[64 + lane] = e1 / ss;
      }
      __syncthreads();
      {  // coalesced ctx: per-wave partials over strided j, combine in LDS
        float cp[8];
#pragma unroll
        for (int k2 = 0; k2 < 8; k2++) cp[k2] = 0.f;
        for (int j = wv; j < TI; j += 4) {
          float spj = sp[j];
          const float* E = p.eout + (size_t)j * HH;
#pragma unroll
          for (int k2 = 0; k2 < 8; k2++) cp[k2] += spj * cldf(&E[k2 * 64 + lane]);
        }
#pragma unroll
        for (int k2 = 0; k2 < 8; k2++) cpart[wv * HH + k2 * 64 + lane] = cp[k2];
      }
      __syncthreads();
      for (int i = tid; i < HH; i += NTHR)
        sctx[i] = ((cpart[0 * HH + i] + cpart[1 * HH + i]) + cpart[2 * HH + i]) + cpart[3 * HH + i];
      __syncthreads();
      for (int k = wv; k < 64; k += 4) {
        int u = q * 64 + k;
        const float* W = p.Wc + (size_t)u * (2 * HH);
        float s0 = 0.f, s1 = 0.f;
#pragma unroll
        for (int j = 0; j < 8; j++) {
          int o = j * 64 + lane;
          s0 += W[o] * srnn[o];
          s1 += W[HH + o] * sctx[o];
        }
        float r0 = wredf(s0), r1 = wredf(s1);
        if (lane == 0) cstf(&p.cc[b * HH + u], tanhf(r0 + r1 + p.bc[u]));
      }
      bar_arrive(c3, wg & 7);  // 5 arrivals per line (wg 0..39)
    }
    if (wg == 0) {
      bar_wait8<1>(c3, (unsigned)(5 * (t + 1)));
      if (tid == 0)
        __hip_atomic_store(f3, (unsigned)(t + 1), __ATOMIC_RELAXED, __HIP_MEMORY_SCOPE_AGENT);
    } else {
      flag_wait<4>(f3, (unsigned)(t + 1));
    }

    // ---- P5: logits chunk (125 rows/WG, 2-deep row pipeline) + partial top5 + exp-sum ----
    {
      float* scc = sm;            // [NB][HH]
      float* slg = sm + NB * HH;  // [NB][125]
      for (int i = tid; i < NB * HH; i += NTHR) scc[i] = cldf(&p.cc[i]);
      __syncthreads();
      const int vbase = wg * 125;
      float wnxt[8];
      {
        const float* W = p.Wout + (size_t)(vbase + wv) * HH;
#pragma unroll
        for (int j = 0; j < 8; j++) wnxt[j] = W[j * 64 + lane];
      }
      for (int r = wv; r < 125; r += 4) {
        float wcur[8];
#pragma unroll
        for (int j = 0; j < 8; j++) wcur[j] = wnxt[j];
        if (r + 4 < 125) {
          const float* W2 = p.Wout + (size_t)(vbase + r + 4) * HH;
#pragma unroll
          for (int j = 0; j < 8; j++) wnxt[j] = W2[j * 64 + lane];
        }
        float a0 = 0.f, a1 = 0.f, a2 = 0.f, a3 = 0.f, a4 = 0.f;
#pragma unroll
        for (int j = 0; j < 8; j++) {
          float wj = wcur[j];
          int o = j * 64 + lane;
          a0 += wj * scc[0 * HH + o];
          a1 += wj * scc[1 * HH + o];
          a2 += wj * scc[2 * HH + o];
          a3 += wj * scc[3 * HH + o];
          a4 += wj * scc[4 * HH + o];
        }
        float r0 = wredf(a0), r1 = wredf(a1), r2 = wredf(a2), r3 = wredf(a3), r4 = wredf(a4);
        if (lane == 0) {
          float bo = p.bout[vbase + r];
          slg[0 * 125 + r] = r0 + bo;
          slg[1 * 125 + r] = r1 + bo;
          slg[2 * 125 + r] = r2 + bo;
          slg[3 * 125 + r] = r3 + bo;
          slg[4 * 125 + r] = r4 + bo;
        }
      }
      __syncthreads();
      if (wv == 0) {
        for (int b = 0; b < NB; b++) {
          float s0 = (lane < 125) ? expf(slg[b * 125 + lane]) : 0.f;
          float s1 = (lane + 64 < 125) ? expf(slg[b * 125 + lane + 64]) : 0.f;
          float ss = wredf(s0 + s1);
          if (lane == 0) cstf(&p.psum[wg * NB + b], ss);
        }
      } else if (wv == 1 && lane < NB) {
        int b = lane;
        float bv[5]; int bidx[5];
#pragma unroll
        for (int k = 0; k < 5; k++) { bv[k] = -INFINITY; bidx[k] = 0x7fffffff; }
        for (int r = 0; r < 125; r++) {
          float v = slg[b * 125 + r];
          if (v > bv[4]) {  // strict >: equal values keep earlier (lower) index
            int k = 4;
            while (k > 0 && v > bv[k - 1]) { bv[k] = bv[k - 1]; bidx[k] = bidx[k - 1]; k--; }
            bv[k] = v; bidx[k] = vbase + r;
          }
        }
#pragma unroll
        for (int k = 0; k < 5; k++) {
          cstf(&p.ptop_v[(wg * NB + b) * 5 + k], bv[k]);
          csti(&p.ptop_i[(wg * NB + b) * 5 + k], bidx[k]);
        }
      }
    }
    bar_arrive(c5, wg >> 5);

    // ---- P6: merge (WG 0 only) ----
    if (wg == 0) {
      bar_wait8<1>(c5, (unsigned)(32 * (t + 1)));
      float* sval = sm;                  // [256][5]
      int* sidx = (int*)(sm + 1280);     // [256][5]
      float* sls = sm + 2560;            // [5]
      float* smv = sm + 2576;            // [5][5]
      int* smi = (int*)(sm + 2608);      // [5][5]
      if (wv == 0) {
        for (int b = 0; b < NB; b++) {
          float q0 = cldf(&p.psum[(lane + 0) * NB + b]);
          float q1 = cldf(&p.psum[(lane + 64) * NB + b]);
          float q2 = cldf(&p.psum[(lane + 128) * NB + b]);
          float q3 = cldf(&p.psum[(lane + 192) * NB + b]);
          float s = wredf((q0 + q1) + (q2 + q3));
          if (lane == 0) sls[b] = logf(s);
        }
      }
      __syncthreads();
      for (int b = 0; b < NB; b++) {
#pragma unroll
        for (int k = 0; k < 5; k++) {
          sval[tid * 5 + k] = cldf(&p.ptop_v[(tid * NB + b) * 5 + k]);
          sidx[tid * 5 + k] = cldi(&p.ptop_i[(tid * NB + b) * 5 + k]);
        }
        __syncthreads();
        for (int n = 128; n >= 1; n >>= 1) {
          if (tid < n) {
            float av[5], bv[5], ov[5];
            int ai[5], bi2[5], oi[5];
#pragma unroll
            for (int k = 0; k < 5; k++) {
              av[k] = sval[tid * 5 + k]; ai[k] = sidx[tid * 5 + k];
              bv[k] = sval[(tid + n) * 5 + k]; bi2[k] = sidx[(tid + n) * 5 + k];
            }
            int i = 0, j = 0;
#pragma unroll
            for (int k = 0; k < 5; k++) {
              bool ta = (av[i] > bv[j]) || (av[i] == bv[j] && ai[i] < bi2[j]);
              if (ta) { ov[k] = av[i]; oi[k] = ai[i]; i++; }
              else { ov[k] = bv[j]; oi[k] = bi2[j]; j++; }
            }
#pragma unroll
            for (int k = 0; k < 5; k++) { sval[tid * 5 + k] = ov[k]; sidx[tid * 5 + k] = oi[k]; }
          }
          __syncthreads();
        }
        if (tid == 0) {
#pragma unroll
          for (int k = 0; k < 5; k++) { smv[b * 5 + k] = sval[k]; smi[b * 5 + k] = sidx[k]; }
        }
        __syncthreads();
      }
      if (tid == 0) {
        float cand[25]; int ctok[25];
        for (int b = 0; b < NB; b++) {
          float sb = cldf(&p.scores[b]), lb = sls[b];
#pragma unroll
          for (int k = 0; k < 5; k++) {
            cand[b * 5 + k] = sb + (smv[b * 5 + k] - lb);
            ctok[b * 5 + k] = smi[b * 5 + k];
          }
        }
        float s5[5]; int f5[5];
#pragma unroll
        for (int k = 0; k < 5; k++) { s5[k] = -INFINITY; f5[k] = 0x7fffffff; }
        for (int f = 0; f < 25; f++) {
          float v = cand[f];
          if (v > s5[4]) {
            int k = 4;
            while (k > 0 && v > s5[k - 1]) { s5[k] = s5[k - 1]; f5[k] = f5[k - 1]; k--; }
            s5[k] = v; f5[k] = f;
          }
        }
        for (int j2 = 0; j2 < 5; j2++) {
          int fl = f5[j2];
          csti(&p.pars[t * NB + j2], fl / 5);
          csti(&p.toks[t * NB + j2], ctok[fl]);
          csti(&p.cur_tok[j2], ctok[fl]);
        }
        for (int j2 = 0; j2 < 5; j2++) cstf(&p.scores[j2], s5[j2]);
        flag_store(flag6, (unsigned)(t + 1));
      }
    }
  }

  // ========== F: backtrack and write output (seq as float, then score) ==========
  if (wg == 0 && tid == 0) {
    int best = 0;
    float bvv = cldf(&p.scores[0]);
    for (int j = 1; j < NB; j++) {
      float sj = cldf(&p.scores[j]);
      if (sj > bvv) { bvv = sj; best = j; }
    }
    int beam = best;
    for (int tt = TO - 1; tt >= 0; tt--) {
      p.out[tt] = (float)cldi(&p.toks[tt * NB + beam]);
      beam = cldi(&p.pars[tt * NB + beam]);
    }
    p.out[TO] = bvv;
  }
}

extern "C" void kernel_launch(void* const* d_in, const int* in_sizes, int n_in,
                              void* d_out, int out_size, void* d_ws, size_t ws_size,
                              hipStream_t stream) {
  (void)in_sizes; (void)n_in; (void)out_size; (void)ws_size;
  Params p;
  p.seq  = (const int*)d_in[0];
  p.sosp = (const int*)d_in[3];
  p.emb  = (const float*)d_in[4];
  p.eWi  = (const float*)d_in[5];
  p.eWh  = (const float*)d_in[6];
  p.ebi  = (const float*)d_in[7];
  p.ebh  = (const float*)d_in[8];
  p.dWi  = (const float*)d_in[9];
  p.dWh  = (const float*)d_in[10];
  p.dbi  = (const float*)d_in[11];
  p.dbh  = (const float*)d_in[12];
  p.Wc   = (const float*)d_in[13];
  p.bc   = (const float*)d_in[14];
  p.Wout = (const float*)d_in[15];
  p.bout = (const float*)d_in[16];

  char* w = (char*)d_ws;
  size_t off = 0;
  auto alloc = [&](size_t words) -> char* {
    char* r = w + off;
    off += words * 4;
    off = (off + 255) & ~(size_t)255;
    return r;
  };
  p.bar     = (unsigned*)alloc(2048);         // 51 lines x 128B used (memset below)
  p.cur_tok = (int*)alloc(8);
  p.toks    = (int*)alloc(TO * NB);
  p.pars    = (int*)alloc(TO * NB);
  p.ptop_i  = (int*)alloc(NWG * NB * 5);
  p.gi0     = (float*)alloc((size_t)TI * G3);
  p.eout    = (float*)alloc((size_t)TI * HH);
  p.h0b     = (float*)alloc(2 * HH);
  p.h1b     = (float*)alloc(2 * HH);
  p.dch     = (float*)alloc(2 * 2 * NB * HH);
  p.cc      = (float*)alloc(NB * HH);
  p.ptop_v  = (float*)alloc(NWG * NB * 5);
  p.psum    = (float*)alloc(NWG * NB);
  p.scores  = (float*)alloc(8);
  p.out     = (float*)d_out;

  (void)hipMemsetAsync(d_ws, 0, 8192, stream);  // zero all counter/flag lines
  // Plain launch: 256 WGs x 256 thr at 1 WG/CU on 256 CUs -> co-resident.
  // hipLaunchCooperativeKernel silently rejects at VGPR=256 (r4/r5 failure).
  bsd_kernel<<<dim3(NWG), dim3(NTHR), 0, stream>>>(p);
}

// Round 9
// 15648.949 us; speedup vs baseline: 3.1082x; 1.0575x over previous
//
#include <hip/hip_runtime.h>
#include <math.h>

// ---------------- problem dims ----------------
#define VV 32000
#define HH 512
#define G3 1536   // 3*HH
#define TI 128    // encoder length
#define TO 64     // max decode length
#define NB 5      // beam width
#define NEGF (-1000000000.0f)

// ---------------- grid config ----------------
#define NWG 256
#define NTHR 256
#define KGRU 64   // WGs running encoder recurrence + decoder GRU
#define KPA 40    // WGs running attention+Wc phase (8 per beam)
#define LSTR 32   // words per counter/flag line (128B)

struct Params {
  const int* seq;
  const int* sosp;
  const float *emb, *eWi, *eWh, *ebi, *ebh;
  const float *dWi, *dWh, *dbi, *dbh;
  const float *Wc, *bc, *Wout, *bout;
  unsigned* bar;
  int *cur_tok, *toks, *pars, *ptop_i;
  float *gi0, *eout, *h0b, *h1b, *dch, *cc, *ptop_v, *psum, *scores;
  float* out;
};

// Relaxed agent-scope data movement: reaches the coherence point (bypasses
// stale L1/L2), no cache-maintenance ops. Proven bit-exact in round 8.
__device__ __forceinline__ float cldf(const float* p) {
  return __hip_atomic_load(p, __ATOMIC_RELAXED, __HIP_MEMORY_SCOPE_AGENT);
}
__device__ __forceinline__ void cstf(float* p, float v) {
  __hip_atomic_store(p, v, __ATOMIC_RELAXED, __HIP_MEMORY_SCOPE_AGENT);
}
__device__ __forceinline__ int cldi(const int* p) {
  return __hip_atomic_load(p, __ATOMIC_RELAXED, __HIP_MEMORY_SCOPE_AGENT);
}
__device__ __forceinline__ void csti(int* p, int v) {
  __hip_atomic_store(p, v, __ATOMIC_RELAXED, __HIP_MEMORY_SCOPE_AGENT);
}
__device__ __forceinline__ unsigned rldu(const unsigned* p) {
  return __hip_atomic_load(p, __ATOMIC_RELAXED, __HIP_MEMORY_SCOPE_AGENT);
}

// arrivals split over 8 lines (myline in [0,8)) to de-serialize RMWs.
// __syncthreads() first: all this WG's data stores are vm-drained (at the
// coherence point, since data uses sc-relaxed ops) before the counter RMW.
__device__ __forceinline__ void bar_arrive(unsigned* lines, int myline) {
  __syncthreads();
  if (threadIdx.x == 0)
    __hip_atomic_fetch_add(lines + myline * LSTR, 1u,
                           __ATOMIC_RELAXED, __HIP_MEMORY_SCOPE_AGENT);
}
// aggregator (ONE workgroup): wave0 lanes 0..7 poll the 8 arrival lines
// -> exactly 1 poller per line.
template <int SLP>
__device__ __forceinline__ void agg_wait8(const unsigned* lines, unsigned tgt) {
  if (threadIdx.x < 64) {
    for (;;) {
      unsigned v = tgt;
      if (threadIdx.x < 8) v = rldu(lines + threadIdx.x * LSTR);
      if (__all(v >= tgt)) break;
      __builtin_amdgcn_s_sleep(SLP);
    }
  }
  __syncthreads();
}
// broadcast: producer/aggregator tid0 stores token to NL leaf lines
// (fire-and-forget). Waiters poll ONE leaf line (<=16 pollers/line).
__device__ __forceinline__ void bcast_store(unsigned* L, int NL, unsigned tok) {
  asm volatile("s_waitcnt vmcnt(0)" ::: "memory");  // own data at coherence pt
  for (int i = 0; i < NL; i++)
    __hip_atomic_store(L + i * LSTR, tok, __ATOMIC_RELAXED, __HIP_MEMORY_SCOPE_AGENT);
}
template <int SLP>
__device__ __forceinline__ void leaf_wait(const unsigned* L, int grp, unsigned tok) {
  if (threadIdx.x == 0) {
    while (rldu(L + grp * LSTR) < tok) __builtin_amdgcn_s_sleep(SLP);
  }
  __syncthreads();
}

__device__ __forceinline__ float wredf(float v) {
#pragma unroll
  for (int o = 32; o; o >>= 1) v += __shfl_xor(v, o, 64);
  return v;
}

// Decoder GRU layer over KGRU WGs, weights register-resident.
template <int LAYER>
__device__ void dec_gru_reg(const Params& p, float* sm, int t, int ib, int ob,
                            const float (&wd)[12][8]) {
  const int wg = blockIdx.x, tid = threadIdx.x;
  const int lane = tid & 63, wv = tid >> 6;
  float* sx = sm;                 // [NB][HH]
  float* sh = sm + NB * HH;       // [NB][HH]
  float* fres = sm + 2 * NB * HH; // [48][NB]

  int ct[NB], pr[NB];
#pragma unroll
  for (int b = 0; b < NB; b++) {
    ct[b] = (LAYER == 0) ? cldi(&p.cur_tok[b]) : 0;
    pr[b] = (t == 0) ? b : cldi(&p.pars[(t - 1) * NB + b]);
  }
  for (int i = tid; i < NB * HH; i += NTHR) {
    int b = i / HH, u = i - b * HH;
    float xv;
    if (LAYER == 0) xv = p.emb[(size_t)ct[b] * HH + u];               // read-only, cached
    else            xv = cldf(&p.dch[((size_t)(ob * 2 + 0) * NB + b) * HH + u]);
    sx[i] = xv;
    sh[i] = cldf(&p.dch[((size_t)(ib * 2 + LAYER) * NB + pr[b]) * HH + u]);
  }
  __syncthreads();
#pragma unroll
  for (int k = 0; k < 12; k++) {
    const int m_ = k % 6;                  // f%6 == k%6 since f = wv*12 + k
    const int f = wv * 12 + k;
    const float* vecb = (m_ >= 3) ? sh : sx;
    float a0 = 0.f, a1 = 0.f, a2 = 0.f, a3 = 0.f, a4 = 0.f;
#pragma unroll
    for (int j = 0; j < 8; j++) {
      float wj = wd[k][j];
      int o = j * 64 + lane;
      a0 += wj * vecb[0 * HH + o];
      a1 += wj * vecb[1 * HH + o];
      a2 += wj * vecb[2 * HH + o];
      a3 += wj * vecb[3 * HH + o];
      a4 += wj * vecb[4 * HH + o];
    }
    float r0 = wredf(a0), r1 = wredf(a1), r2 = wredf(a2), r3 = wredf(a3), r4 = wredf(a4);
    if (lane == 0) {
      fres[f * NB + 0] = r0; fres[f * NB + 1] = r1; fres[f * NB + 2] = r2;
      fres[f * NB + 3] = r3; fres[f * NB + 4] = r4;
    }
  }
  __syncthreads();
  if (tid < 8 * NB) {
    int ul = tid / NB, b = tid - ul * NB;
    int u = wg * 8 + ul;
    const float* bi = p.dbi + LAYER * G3;
    const float* bh = p.dbh + LAYER * G3;
    float ir = fres[(ul * 6 + 0) * NB + b] + bi[u];
    float iz = fres[(ul * 6 + 1) * NB + b] + bi[HH + u];
    float inn = fres[(ul * 6 + 2) * NB + b] + bi[2 * HH + u];
    float hr = fres[(ul * 6 + 3) * NB + b] + bh[u];
    float hz = fres[(ul * 6 + 4) * NB + b] + bh[HH + u];
    float hn = fres[(ul * 6 + 5) * NB + b] + bh[2 * HH + u];
    float hp = sh[b * HH + u];
    float r = 1.f / (1.f + expf(-(ir + hr)));
    float z = 1.f / (1.f + expf(-(iz + hz)));
    float n = tanhf(inn + r * hn);
    cstf(&p.dch[((size_t)(ob * 2 + LAYER) * NB + b) * HH + u], (1.f - z) * n + z * hp);
  }
}

__global__ void __launch_bounds__(NTHR, 1) bsd_kernel(Params p) {
  const int wg = blockIdx.x, tid = threadIdx.x;
  const int lane = tid & 63, wv = tid >> 6;
  __shared__ float sm[5504];

  // line layout (each line = 128 B)
  unsigned* c1A   = p.bar + 0 * LSTR;    // 8 arrival lines
  unsigned* c1L   = p.bar + 8 * LSTR;    // 8 leaf lines (64-domain bcast)
  unsigned* c2A   = p.bar + 16 * LSTR;   // 8
  unsigned* c2L   = p.bar + 24 * LSTR;   // 5 used (40-domain)
  unsigned* c3A   = p.bar + 32 * LSTR;   // 8
  unsigned* c5A   = p.bar + 40 * LSTR;   // 8
  unsigned* ceA   = p.bar + 48 * LSTR;   // 8
  unsigned* ceL   = p.bar + 56 * LSTR;   // 8
  unsigned* cgA   = p.bar + 64 * LSTR;   // 8
  unsigned* cgL   = p.bar + 72 * LSTR;   // 16
  unsigned* f6L   = p.bar + 88 * LSTR;   // 16 (flag6 leaves)
  unsigned* f3L   = p.bar + 104 * LSTR;  // 16
  unsigned* feL   = p.bar + 120 * LSTR;  // 16 (fenc leaves)

  // ========== E0: gi0[t][row] = emb[seq[t]] . eWi0[row] + ebi0[row]; zero h ==========
  {
    if (wg == 0) {
      for (int i = tid; i < 2 * HH; i += NTHR) { cstf(&p.h0b[i], 0.f); cstf(&p.h1b[i], 0.f); }
    }
    for (int lr = wv; lr < 6; lr += 4) {
      int row = wg * 6 + lr;
      const float* W = p.eWi + (size_t)row * HH;
      float w0[8];
#pragma unroll
      for (int j = 0; j < 8; j++) w0[j] = W[j * 64 + lane];
      float bi = p.ebi[row];
      for (int t = 0; t < TI; t++) {
        const float* x = p.emb + (size_t)p.seq[t] * HH;
        float s = 0.f;
#pragma unroll
        for (int j = 0; j < 8; j++) s += w0[j] * x[j * 64 + lane];
        s = wredf(s);
        if (lane == 0) cstf(&p.gi0[(size_t)t * G3 + row], s + bi);
      }
    }
  }
  // grid barrier #1 (tok 1)
  bar_arrive(cgA, wg & 7);
  if (wg == 0) {
    agg_wait8<2>(cgA, 32u * 1u);
    if (tid == 0) bcast_store(cgL, 16, 1u);
  } else {
    leaf_wait<4>(cgL, wg >> 4, 1u);
  }

  // ========== E1: recurrence on KGRU WGs, register weights, 129 mini-barriers ==========
  if (wg < KGRU) {
    float wreg[24][8];  // L0 waves: rows [uu*3+g]; L1 waves: rows [uu*6+mg]
    if (wv < 2) {
#pragma unroll
      for (int uu = 0; uu < 4; uu++) {
        int u = wg * 8 + wv * 4 + uu;
#pragma unroll
        for (int g = 0; g < 3; g++) {
          const float* W = p.eWh + (size_t)(g * HH + u) * HH;
#pragma unroll
          for (int j = 0; j < 8; j++) wreg[uu * 3 + g][j] = W[j * 64 + lane];
        }
      }
    } else {
#pragma unroll
      for (int uu = 0; uu < 4; uu++) {
        int u = wg * 8 + (wv - 2) * 4 + uu;
#pragma unroll
        for (int g = 0; g < 3; g++) {
          const float* Wi1 = p.eWi + (size_t)G3 * HH + (size_t)(g * HH + u) * HH;
          const float* Wh1 = p.eWh + (size_t)G3 * HH + (size_t)(g * HH + u) * HH;
#pragma unroll
          for (int j = 0; j < 8; j++) {
            wreg[uu * 6 + g][j] = Wi1[j * 64 + lane];
            wreg[uu * 6 + 3 + g][j] = Wh1[j * 64 + lane];
          }
        }
      }
    }
    for (int T = 0; T <= TI; T++) {
      const int sIn = T & 1, sOut = sIn ^ 1;
      if (wv < 2) {
        if (T < TI) {
          float hv[8];
#pragma unroll
          for (int j = 0; j < 8; j++) hv[j] = cldf(&p.h0b[sIn * HH + j * 64 + lane]);
#pragma unroll
          for (int uu = 0; uu < 4; uu++) {
            int u = wg * 8 + wv * 4 + uu;
            float g[3];
#pragma unroll
            for (int gg = 0; gg < 3; gg++) {
              float s = 0.f;
#pragma unroll
              for (int j = 0; j < 8; j++) s += wreg[uu * 3 + gg][j] * hv[j];
              g[gg] = wredf(s);
            }
            if (lane == 0) {
              const float* gr = p.gi0 + (size_t)T * G3;
              float ir = cldf(&gr[u]), iz = cldf(&gr[HH + u]), inn = cldf(&gr[2 * HH + u]);
              float hr = g[0] + p.ebh[u], hz = g[1] + p.ebh[HH + u], hn = g[2] + p.ebh[2 * HH + u];
              float r = 1.f / (1.f + expf(-(ir + hr)));
              float z = 1.f / (1.f + expf(-(iz + hz)));
              float n = tanhf(inn + r * hn);
              float hp = cldf(&p.h0b[sIn * HH + u]);
              cstf(&p.h0b[sOut * HH + u], (1.f - z) * n + z * hp);
            }
          }
        }
      } else {
        if (T >= 1) {
          float xv[8], hv[8];
#pragma unroll
          for (int j = 0; j < 8; j++) {
            xv[j] = cldf(&p.h0b[sIn * HH + j * 64 + lane]);
            hv[j] = cldf(&p.h1b[sOut * HH + j * 64 + lane]);
          }
#pragma unroll
          for (int uu = 0; uu < 4; uu++) {
            int u = wg * 8 + (wv - 2) * 4 + uu;
            float gi[3], gh[3];
#pragma unroll
            for (int gg = 0; gg < 3; gg++) {
              float si = 0.f, s2 = 0.f;
#pragma unroll
              for (int j = 0; j < 8; j++) {
                si += wreg[uu * 6 + gg][j] * xv[j];
                s2 += wreg[uu * 6 + 3 + gg][j] * hv[j];
              }
              gi[gg] = wredf(si);
              gh[gg] = wredf(s2);
            }
            if (lane == 0) {
              const float* bi = p.ebi + G3;
              const float* bh = p.ebh + G3;
              float ir = gi[0] + bi[u], iz = gi[1] + bi[HH + u], inn = gi[2] + bi[2 * HH + u];
              float hr = gh[0] + bh[u], hz = gh[1] + bh[HH + u], hn = gh[2] + bh[2 * HH + u];
              float r = 1.f / (1.f + expf(-(ir + hr)));
              float z = 1.f / (1.f + expf(-(iz + hz)));
              float n = tanhf(inn + r * hn);
              float hp = cldf(&p.h1b[sOut * HH + u]);
              float hnew = (1.f - z) * n + z * hp;
              cstf(&p.h1b[sIn * HH + u], hnew);
              cstf(&p.eout[(size_t)(T - 1) * HH + u], hnew);
            }
          }
        }
      }
      // 64-domain barrier, tok = T+1
      bar_arrive(ceA, wg & 7);
      if (wg == 0) {
        agg_wait8<1>(ceA, (unsigned)(8 * (T + 1)));
        if (tid == 0) bcast_store(ceL, 8, (unsigned)(T + 1));
      } else {
        leaf_wait<2>(ceL, wg >> 3, (unsigned)(T + 1));
      }
    }
    if (wg == 0 && tid == 0) bcast_store(feL, 16, 1u);
  } else {
    leaf_wait<16>(feL, wg >> 4, 1u);
  }

  // ---- load decoder GRU weights into registers (KGRU WGs), both layers ----
  float wdec[2][12][8];
  if (wg < KGRU) {
#pragma unroll
    for (int k = 0; k < 12; k++) {
      const int f = wv * 12 + k;
      const int ul = f / 6, m_ = f % 6;
      const int u = wg * 8 + ul;
      const float* W0 = (m_ < 3 ? p.dWi : p.dWh) + (size_t)((m_ % 3) * HH + u) * HH;
      const float* W1 = (m_ < 3 ? p.dWi : p.dWh) + (size_t)G3 * HH + (size_t)((m_ % 3) * HH + u) * HH;
#pragma unroll
      for (int j = 0; j < 8; j++) { wdec[0][k][j] = W0[j * 64 + lane]; wdec[1][k][j] = W1[j * 64 + lane]; }
    }
  }

  // ========== D0: broadcast enc_hidden to beams, init tokens/scores ==========
  {
    for (int i = tid + wg * NTHR; i < 2 * NB * HH; i += NWG * NTHR) {
      int l = i / (NB * HH);
      int rem = i - l * (NB * HH);
      int u = rem % HH;
      float hv = (l == 0) ? cldf(&p.h0b[u]) : cldf(&p.h1b[u]);
      cstf(&p.dch[(size_t)l * NB * HH + rem], hv);
    }
    if (wg == 0 && tid < NB) {
      csti(&p.cur_tok[tid], p.sosp[0]);
      cstf(&p.scores[tid], (tid == 0) ? 0.f : NEGF);
    }
  }
  // grid barrier #2 (tok 2)
  bar_arrive(cgA, wg & 7);
  if (wg == 0) {
    agg_wait8<2>(cgA, 32u * 2u);
    if (tid == 0) bcast_store(cgL, 16, 2u);
  } else {
    leaf_wait<4>(cgL, wg >> 4, 2u);
  }

  // ========== decoder: 64 steps ==========
  for (int t = 0; t < TO; t++) {
    const int ib = t & 1, ob = ib ^ 1;

    // step-t inputs ready (flag6 == t; trivially true at t=0)
    if (wg != 0) leaf_wait<8>(f6L, wg >> 4, (unsigned)t);
    else __syncthreads();

    if (wg < KGRU) {
      dec_gru_reg<0>(p, sm, t, ib, ob, wdec[0]);
      bar_arrive(c1A, wg & 7);
      if (wg == 0) {
        agg_wait8<2>(c1A, (unsigned)(8 * (t + 1)));
        if (tid == 0) bcast_store(c1L, 8, (unsigned)(t + 1));
      } else {
        leaf_wait<4>(c1L, wg >> 3, (unsigned)(t + 1));
      }
      dec_gru_reg<1>(p, sm, t, ib, ob, wdec[1]);
      bar_arrive(c2A, wg & 7);
    }

    // ---- PA: attention + ctx + Wc + tanh (40 WGs, 8 per beam) ----
    if (wg < KPA) {
      if (wg == 0) {
        agg_wait8<2>(c2A, (unsigned)(8 * (t + 1)));
        if (tid == 0) bcast_store(c2L, 5, (unsigned)(t + 1));
      } else {
        leaf_wait<4>(c2L, wg >> 3, (unsigned)(t + 1));
      }
      const int b = wg / 8, q = wg % 8;
      float* srnn = sm;            // 512
      float* sp = sm + 512;        // 128
      float* cpart = sm + 640;     // [4][512]
      float* sctx = sm + 2688;     // 512
      for (int i = tid; i < HH; i += NTHR)
        srnn[i] = cldf(&p.dch[((size_t)(ob * 2 + 1) * NB + b) * HH + i]);
      __syncthreads();
      for (int j = wv; j < TI; j += 4) {
        const float* E = p.eout + (size_t)j * HH;
        float s = 0.f;
#pragma unroll
        for (int k2 = 0; k2 < 8; k2++) s += srnn[k2 * 64 + lane] * cldf(&E[k2 * 64 + lane]);
        s = wredf(s);
        if (lane == 0) sp[j] = s;
      }
      __syncthreads();
      if (wv == 0) {
        float v0 = sp[lane], v1 = sp[64 + lane];
        float mx = fmaxf(v0, v1);
#pragma unroll
        for (int o = 32; o; o >>= 1) mx = fmaxf(mx, __shfl_xor(mx, o, 64));
        float e0 = expf(v0 - mx), e1 = expf(v1 - mx);
        float ss = wredf(e0 + e1);
        sp[lane] = e0 / ss;
        sp[64 + lane] = e1 / ss;
      }
      __syncthreads();
      {  // coalesced ctx: per-wave partials over strided j, combine in LDS
        float cp[8];
#pragma unroll
        for (int k2 = 0; k2 < 8; k2++) cp[k2] = 0.f;
        for (int j = wv; j < TI; j += 4) {
          float spj = sp[j];
          const float* E = p.eout + (size_t)j * HH;
#pragma unroll
          for (int k2 = 0; k2 < 8; k2++) cp[k2] += spj * cldf(&E[k2 * 64 + lane]);
        }
#pragma unroll
        for (int k2 = 0; k2 < 8; k2++) cpart[wv * HH + k2 * 64 + lane] = cp[k2];
      }
      __syncthreads();
      for (int i = tid; i < HH; i += NTHR)
        sctx[i] = ((cpart[0 * HH + i] + cpart[1 * HH + i]) + cpart[2 * HH + i]) + cpart[3 * HH + i];
      __syncthreads();
      for (int k = wv; k < 64; k += 4) {
        int u = q * 64 + k;
        const float* W = p.Wc + (size_t)u * (2 * HH);
        float s0 = 0.f, s1 = 0.f;
#pragma unroll
        for (int j = 0; j < 8; j++) {
          int o = j * 64 + lane;
          s0 += W[o] * srnn[o];
          s1 += W[HH + o] * sctx[o];
        }
        float r0 = wredf(s0), r1 = wredf(s1);
        if (lane == 0) cstf(&p.cc[b * HH + u], tanhf(r0 + r1 + p.bc[u]));
      }
      bar_arrive(c3A, wg & 7);  // 5 arrivals per line
    }
    if (wg == 0) {
      agg_wait8<2>(c3A, (unsigned)(5 * (t + 1)));
      if (tid == 0) bcast_store(f3L, 16, (unsigned)(t + 1));
      __syncthreads();
    } else {
      leaf_wait<8>(f3L, wg >> 4, (unsigned)(t + 1));
    }

    // ---- P5: logits chunk (125 rows/WG, 2-deep row pipeline) + partial top5 + exp-sum ----
    {
      float* scc = sm;            // [NB][HH]
      float* slg = sm + NB * HH;  // [NB][125]
      for (int i = tid; i < NB * HH; i += NTHR) scc[i] = cldf(&p.cc[i]);
      __syncthreads();
      const int vbase = wg * 125;
      float wnxt[8];
      {
        const float* W = p.Wout + (size_t)(vbase + wv) * HH;
#pragma unroll
        for (int j = 0; j < 8; j++) wnxt[j] = W[j * 64 + lane];
      }
      for (int r = wv; r < 125; r += 4) {
        float wcur[8];
#pragma unroll
        for (int j = 0; j < 8; j++) wcur[j] = wnxt[j];
        if (r + 4 < 125) {
          const float* W2 = p.Wout + (size_t)(vbase + r + 4) * HH;
#pragma unroll
          for (int j = 0; j < 8; j++) wnxt[j] = W2[j * 64 + lane];
        }
        float a0 = 0.f, a1 = 0.f, a2 = 0.f, a3 = 0.f, a4 = 0.f;
#pragma unroll
        for (int j = 0; j < 8; j++) {
          float wj = wcur[j];
          int o = j * 64 + lane;
          a0 += wj * scc[0 * HH + o];
          a1 += wj * scc[1 * HH + o];
          a2 += wj * scc[2 * HH + o];
          a3 += wj * scc[3 * HH + o];
          a4 += wj * scc[4 * HH + o];
        }
        float r0 = wredf(a0), r1 = wredf(a1), r2 = wredf(a2), r3 = wredf(a3), r4 = wredf(a4);
        if (lane == 0) {
          float bo = p.bout[vbase + r];
          slg[0 * 125 + r] = r0 + bo;
          slg[1 * 125 + r] = r1 + bo;
          slg[2 * 125 + r] = r2 + bo;
          slg[3 * 125 + r] = r3 + bo;
          slg[4 * 125 + r] = r4 + bo;
        }
      }
      __syncthreads();
      if (wv == 0) {
        for (int b = 0; b < NB; b++) {
          float s0 = (lane < 125) ? expf(slg[b * 125 + lane]) : 0.f;
          float s1 = (lane + 64 < 125) ? expf(slg[b * 125 + lane + 64]) : 0.f;
          float ss = wredf(s0 + s1);
          if (lane == 0) cstf(&p.psum[wg * NB + b], ss);
        }
      } else if (wv == 1 && lane < NB) {
        int b = lane;
        float bv[5]; int bidx[5];
#pragma unroll
        for (int k = 0; k < 5; k++) { bv[k] = -INFINITY; bidx[k] = 0x7fffffff; }
        for (int r = 0; r < 125; r++) {
          float v = slg[b * 125 + r];
          if (v > bv[4]) {  // strict >: equal values keep earlier (lower) index
            int k = 4;
            while (k > 0 && v > bv[k - 1]) { bv[k] = bv[k - 1]; bidx[k] = bidx[k - 1]; k--; }
            bv[k] = v; bidx[k] = vbase + r;
          }
        }
#pragma unroll
        for (int k = 0; k < 5; k++) {
          cstf(&p.ptop_v[(wg * NB + b) * 5 + k], bv[k]);
          csti(&p.ptop_i[(wg * NB + b) * 5 + k], bidx[k]);
        }
      }
    }
    bar_arrive(c5A, wg & 7);

    // ---- P6: merge (WG 0 only) ----
    if (wg == 0) {
      agg_wait8<2>(c5A, (unsigned)(32 * (t + 1)));
      float* sval = sm;                  // [256][5]
      int* sidx = (int*)(sm + 1280);     // [256][5]
      float* sls = sm + 2560;            // [5]
      float* smv = sm + 2576;            // [5][5]
      int* smi = (int*)(sm + 2608);      // [5][5]
      if (wv == 0) {
        for (int b = 0; b < NB; b++) {
          float q0 = cldf(&p.psum[(lane + 0) * NB + b]);
          float q1 = cldf(&p.psum[(lane + 64) * NB + b]);
          float q2 = cldf(&p.psum[(lane + 128) * NB + b]);
          float q3 = cldf(&p.psum[(lane + 192) * NB + b]);
          float s = wredf((q0 + q1) + (q2 + q3));
          if (lane == 0) sls[b] = logf(s);
        }
      }
      __syncthreads();
      for (int b = 0; b < NB; b++) {
#pragma unroll
        for (int k = 0; k < 5; k++) {
          sval[tid * 5 + k] = cldf(&p.ptop_v[(tid * NB + b) * 5 + k]);
          sidx[tid * 5 + k] = cldi(&p.ptop_i[(tid * NB + b) * 5 + k]);
        }
        __syncthreads();
        for (int n = 128; n >= 1; n >>= 1) {
          if (tid < n) {
            float av[5], bv[5], ov[5];
            int ai[5], bi2[5], oi[5];
#pragma unroll
            for (int k = 0; k < 5; k++) {
              av[k] = sval[tid * 5 + k]; ai[k] = sidx[tid * 5 + k];
              bv[k] = sval[(tid + n) * 5 + k]; bi2[k] = sidx[(tid + n) * 5 + k];
            }
            int i = 0, j = 0;
#pragma unroll
            for (int k = 0; k < 5; k++) {
              bool ta = (av[i] > bv[j]) || (av[i] == bv[j] && ai[i] < bi2[j]);
              if (ta) { ov[k] = av[i]; oi[k] = ai[i]; i++; }
              else { ov[k] = bv[j]; oi[k] = bi2[j]; j++; }
            }
#pragma unroll
            for (int k = 0; k < 5; k++) { sval[tid * 5 + k] = ov[k]; sidx[tid * 5 + k] = oi[k]; }
          }
          __syncthreads();
        }
        if (tid == 0) {
#pragma unroll
          for (int k = 0; k < 5; k++) { smv[b * 5 + k] = sval[k]; smi[b * 5 + k] = sidx[k]; }
        }
        __syncthreads();
      }
      if (tid == 0) {
        float cand[25]; int ctok[25];
        for (int b = 0; b < NB; b++) {
          float sb = cldf(&p.scores[b]), lb = sls[b];
#pragma unroll
          for (int k = 0; k < 5; k++) {
            cand[b * 5 + k] = sb + (smv[b * 5 + k] - lb);
            ctok[b * 5 + k] = smi[b * 5 + k];
          }
        }
        float s5[5]; int f5[5];
#pragma unroll
        for (int k = 0; k < 5; k++) { s5[k] = -INFINITY; f5[k] = 0x7fffffff; }
        for (int f = 0; f < 25; f++) {
          float v = cand[f];
          if (v > s5[4]) {
            int k = 4;
            while (k > 0 && v > s5[k - 1]) { s5[k] = s5[k - 1]; f5[k] = f5[k - 1]; k--; }
            s5[k] = v; f5[k] = f;
          }
        }
        for (int j2 = 0; j2 < 5; j2++) {
          int fl = f5[j2];
          csti(&p.pars[t * NB + j2], fl / 5);
          csti(&p.toks[t * NB + j2], ctok[fl]);
          csti(&p.cur_tok[j2], ctok[fl]);
        }
        for (int j2 = 0; j2 < 5; j2++) cstf(&p.scores[j2], s5[j2]);
        bcast_store(f6L, 16, (unsigned)(t + 1));
      }
    }
  }

  // ========== F: backtrack and write output (seq as float, then score) ==========
  if (wg == 0 && tid == 0) {
    int best = 0;
    float bvv = cldf(&p.scores[0]);
    for (int j = 1; j < NB; j++) {
      float sj = cldf(&p.scores[j]);
      if (sj > bvv) { bvv = sj; best = j; }
    }
    int beam = best;
    for (int tt = TO - 1; tt >= 0; tt--) {
      p.out[tt] = (float)cldi(&p.toks[tt * NB + beam]);
      beam = cldi(&p.pars[tt * NB + beam]);
    }
    p.out[TO] = bvv;
  }
}

extern "C" void kernel_launch(void* const* d_in, const int* in_sizes, int n_in,
                              void* d_out, int out_size, void* d_ws, size_t ws_size,
                              hipStream_t stream) {
  (void)in_sizes; (void)n_in; (void)out_size; (void)ws_size;
  Params p;
  p.seq  = (const int*)d_in[0];
  p.sosp = (const int*)d_in[3];
  p.emb  = (const float*)d_in[4];
  p.eWi  = (const float*)d_in[5];
  p.eWh  = (const float*)d_in[6];
  p.ebi  = (const float*)d_in[7];
  p.ebh  = (const float*)d_in[8];
  p.dWi  = (const float*)d_in[9];
  p.dWh  = (const float*)d_in[10];
  p.dbi  = (const float*)d_in[11];
  p.dbh  = (const float*)d_in[12];
  p.Wc   = (const float*)d_in[13];
  p.bc   = (const float*)d_in[14];
  p.Wout = (const float*)d_in[15];
  p.bout = (const float*)d_in[16];

  char* w = (char*)d_ws;
  size_t off = 0;
  auto alloc = [&](size_t words) -> char* {
    char* r = w + off;
    off += words * 4;
    off = (off + 255) & ~(size_t)255;
    return r;
  };
  p.bar     = (unsigned*)alloc(136 * LSTR);   // 136 lines x 128B (memset below)
  p.cur_tok = (int*)alloc(8);
  p.toks    = (int*)alloc(TO * NB);
  p.pars    = (int*)alloc(TO * NB);
  p.ptop_i  = (int*)alloc(NWG * NB * 5);
  p.gi0     = (float*)alloc((size_t)TI * G3);
  p.eout    = (float*)alloc((size_t)TI * HH);
  p.h0b     = (float*)alloc(2 * HH);
  p.h1b     = (float*)alloc(2 * HH);
  p.dch     = (float*)alloc(2 * 2 * NB * HH);
  p.cc      = (float*)alloc(NB * HH);
  p.ptop_v  = (float*)alloc(NWG * NB * 5);
  p.psum    = (float*)alloc(NWG * NB);
  p.scores  = (float*)alloc(8);
  p.out     = (float*)d_out;

  (void)hipMemsetAsync(d_ws, 0, 136 * LSTR * 4, stream);  // zero all lines
  // Plain launch: 256 WGs x 256 thr at 1 WG/CU on 256 CUs -> co-resident.
  // hipLaunchCooperativeKernel silently rejects at VGPR=256 (r4/r5 failure).
  bsd_kernel<<<dim3(NWG), dim3(NTHR), 0, stream>>>(p);
}

// Round 10
// 14541.069 us; speedup vs baseline: 3.3450x; 1.0762x over previous
//
#include <hip/hip_runtime.h>
#include <math.h>

// ---------------- problem dims ----------------
#define VV 32000
#define HH 512
#define G3 1536   // 3*HH
#define TI 128    // encoder length
#define TO 64     // max decode length
#define NB 5      // beam width
#define NEGF (-1000000000.0f)

// ---------------- grid config ----------------
#define NWG 256
#define NTHR 256
#define KGRU 64   // WGs running encoder recurrence + decoder GRU
#define KPA 40    // WGs running attention+Wc phase (8 per beam)
#define LSTR 32   // words per counter/flag line (128B)

struct Params {
  const int* seq;
  const int* sosp;
  const float *emb, *eWi, *eWh, *ebi, *ebh;
  const float *dWi, *dWh, *dbi, *dbh;
  const float *Wc, *bc, *Wout, *bout;
  unsigned* bar;
  int *cur_tok, *toks, *pars, *ptop_i;
  float *gi0, *eout, *h0b, *h1b, *dch, *cc, *ptop_v, *psum, *scores;
  float* out;
};

// Relaxed agent-scope data movement (coherence-point, no cache-maintenance).
// Proven bit-exact r8/r9. This round: 64-bit pair versions to halve the
// transaction count on all bulk paths.
__device__ __forceinline__ float cldf(const float* p) {
  return __hip_atomic_load(p, __ATOMIC_RELAXED, __HIP_MEMORY_SCOPE_AGENT);
}
__device__ __forceinline__ void cstf(float* p, float v) {
  __hip_atomic_store(p, v, __ATOMIC_RELAXED, __HIP_MEMORY_SCOPE_AGENT);
}
__device__ __forceinline__ int cldi(const int* p) {
  return __hip_atomic_load(p, __ATOMIC_RELAXED, __HIP_MEMORY_SCOPE_AGENT);
}
__device__ __forceinline__ void csti(int* p, int v) {
  __hip_atomic_store(p, v, __ATOMIC_RELAXED, __HIP_MEMORY_SCOPE_AGENT);
}
__device__ __forceinline__ unsigned rldu(const unsigned* p) {
  return __hip_atomic_load(p, __ATOMIC_RELAXED, __HIP_MEMORY_SCOPE_AGENT);
}
typedef unsigned long long u64t;
union F2U { u64t u; float f[2]; };
__device__ __forceinline__ void cld2(float* d, const float* p) {
  F2U x; x.u = __hip_atomic_load((const u64t*)p, __ATOMIC_RELAXED, __HIP_MEMORY_SCOPE_AGENT);
  d[0] = x.f[0]; d[1] = x.f[1];
}
__device__ __forceinline__ void cst2(float* p, float a, float b) {
  F2U x; x.f[0] = a; x.f[1] = b;
  __hip_atomic_store((u64t*)p, x.u, __ATOMIC_RELAXED, __HIP_MEMORY_SCOPE_AGENT);
}

// arrivals split over 8 lines; __syncthreads() drains vmcnt first (data at CP).
__device__ __forceinline__ void bar_arrive(unsigned* lines, int myline) {
  __syncthreads();
  if (threadIdx.x == 0)
    __hip_atomic_fetch_add(lines + myline * LSTR, 1u,
                           __ATOMIC_RELAXED, __HIP_MEMORY_SCOPE_AGENT);
}
// direct poll: wave0 lanes 0..7 poll the 8 lines
template <int SLP>
__device__ __forceinline__ void bar_wait8(const unsigned* lines, unsigned tgt) {
  if (threadIdx.x < 64) {
    for (;;) {
      unsigned v = tgt;
      if (threadIdx.x < 8) v = rldu(lines + threadIdx.x * LSTR);
      if (__all(v >= tgt)) break;
      __builtin_amdgcn_s_sleep(SLP);
    }
  }
  __syncthreads();
}
__device__ __forceinline__ void bcast_store(unsigned* L, int NL, unsigned tok) {
  asm volatile("s_waitcnt vmcnt(0)" ::: "memory");  // own data at CP
  for (int i = 0; i < NL; i++)
    __hip_atomic_store(L + i * LSTR, tok, __ATOMIC_RELAXED, __HIP_MEMORY_SCOPE_AGENT);
}
template <int SLP>
__device__ __forceinline__ void leaf_wait(const unsigned* L, int grp, unsigned tok) {
  if (threadIdx.x == 0) {
    while (rldu(L + grp * LSTR) < tok) __builtin_amdgcn_s_sleep(SLP);
  }
  __syncthreads();
}

__device__ __forceinline__ float wredf(float v) {
#pragma unroll
  for (int o = 32; o; o >>= 1) v += __shfl_xor(v, o, 64);
  return v;
}

// stage a 512-float row from global (pair loads) into LDS; consumed later
// with the ORIGINAL j*64+lane mapping -> bitwise-identical sums.
__device__ __forceinline__ void stage_row(float* dst, const float* src, int lane) {
#pragma unroll
  for (int mp = 0; mp < 4; mp++) {
    float t2[2];
    cld2(t2, &src[mp * 128 + 2 * lane]);
    dst[mp * 128 + 2 * lane] = t2[0];
    dst[mp * 128 + 2 * lane + 1] = t2[1];
  }
}

// Decoder GRU layer over KGRU WGs, weights register-resident. Pair staging;
// LDS content and all downstream arithmetic identical to round 9.
template <int LAYER>
__device__ void dec_gru_reg(const Params& p, float* sm, int t, int ib, int ob,
                            const float (&wd)[12][8]) {
  const int wg = blockIdx.x, tid = threadIdx.x;
  const int lane = tid & 63, wv = tid >> 6;
  float* sx = sm;                 // [NB][HH]
  float* sh = sm + NB * HH;       // [NB][HH]
  float* fres = sm + 2 * NB * HH; // [48][NB]

  int ct[NB], pr[NB];
#pragma unroll
  for (int b = 0; b < NB; b++) {
    ct[b] = (LAYER == 0) ? cldi(&p.cur_tok[b]) : 0;
    pr[b] = (t == 0) ? b : cldi(&p.pars[(t - 1) * NB + b]);
  }
  for (int i = tid; i < NB * (HH / 2); i += NTHR) {  // 1280 pairs
    int b = i >> 8, c = (i & 255) << 1;
    float x2[2], h2[2];
    if (LAYER == 0) {
      const float* e = p.emb + (size_t)ct[b] * HH + c;  // read-only, cached
      x2[0] = e[0]; x2[1] = e[1];
    } else {
      cld2(x2, &p.dch[((size_t)(ob * 2 + 0) * NB + b) * HH + c]);
    }
    cld2(h2, &p.dch[((size_t)(ib * 2 + LAYER) * NB + pr[b]) * HH + c]);
    sx[b * HH + c] = x2[0]; sx[b * HH + c + 1] = x2[1];
    sh[b * HH + c] = h2[0]; sh[b * HH + c + 1] = h2[1];
  }
  __syncthreads();
#pragma unroll
  for (int k = 0; k < 12; k++) {
    const int m_ = k % 6;                  // f%6 == k%6 since f = wv*12 + k
    const int f = wv * 12 + k;
    const float* vecb = (m_ >= 3) ? sh : sx;
    float a0 = 0.f, a1 = 0.f, a2 = 0.f, a3 = 0.f, a4 = 0.f;
#pragma unroll
    for (int j = 0; j < 8; j++) {
      float wj = wd[k][j];
      int o = j * 64 + lane;
      a0 += wj * vecb[0 * HH + o];
      a1 += wj * vecb[1 * HH + o];
      a2 += wj * vecb[2 * HH + o];
      a3 += wj * vecb[3 * HH + o];
      a4 += wj * vecb[4 * HH + o];
    }
    float r0 = wredf(a0), r1 = wredf(a1), r2 = wredf(a2), r3 = wredf(a3), r4 = wredf(a4);
    if (lane == 0) {
      fres[f * NB + 0] = r0; fres[f * NB + 1] = r1; fres[f * NB + 2] = r2;
      fres[f * NB + 3] = r3; fres[f * NB + 4] = r4;
    }
  }
  __syncthreads();
  if (tid < 8 * NB) {
    int ul = tid / NB, b = tid - ul * NB;
    int u = wg * 8 + ul;
    const float* bi = p.dbi + LAYER * G3;
    const float* bh = p.dbh + LAYER * G3;
    float ir = fres[(ul * 6 + 0) * NB + b] + bi[u];
    float iz = fres[(ul * 6 + 1) * NB + b] + bi[HH + u];
    float inn = fres[(ul * 6 + 2) * NB + b] + bi[2 * HH + u];
    float hr = fres[(ul * 6 + 3) * NB + b] + bh[u];
    float hz = fres[(ul * 6 + 4) * NB + b] + bh[HH + u];
    float hn = fres[(ul * 6 + 5) * NB + b] + bh[2 * HH + u];
    float hp = sh[b * HH + u];
    float r = 1.f / (1.f + expf(-(ir + hr)));
    float z = 1.f / (1.f + expf(-(iz + hz)));
    float n = tanhf(inn + r * hn);
    cstf(&p.dch[((size_t)(ob * 2 + LAYER) * NB + b) * HH + u], (1.f - z) * n + z * hp);
  }
}

__global__ void __launch_bounds__(NTHR, 1) bsd_kernel(Params p) {
  const int wg = blockIdx.x, tid = threadIdx.x;
  const int lane = tid & 63, wv = tid >> 6;
  __shared__ float sm[5504];
  __shared__ unsigned s_mrg;

  unsigned* c1A = p.bar + 0 * LSTR;    // 8 lines
  unsigned* c2A = p.bar + 8 * LSTR;    // 8
  unsigned* c3A = p.bar + 16 * LSTR;   // 8
  unsigned* c5A = p.bar + 24 * LSTR;   // 8
  unsigned* c5F = p.bar + 32 * LSTR;   // 1 (last-man final)
  unsigned* ceA = p.bar + 40 * LSTR;   // 8
  unsigned* cgA = p.bar + 48 * LSTR;   // 8
  unsigned* f6L = p.bar + 56 * LSTR;   // 16 flag6 leaves
  unsigned* feL = p.bar + 72 * LSTR;   // 16 fenc leaves

  // ========== E0: gi0[t][row] = emb[seq[t]] . eWi0[row] + ebi0[row]; zero h ==========
  {
    if (wg == 0) {
      for (int i = tid; i < 2 * HH; i += NTHR) { cstf(&p.h0b[i], 0.f); cstf(&p.h1b[i], 0.f); }
    }
    for (int lr = wv; lr < 6; lr += 4) {
      int row = wg * 6 + lr;
      const float* W = p.eWi + (size_t)row * HH;
      float w0[8];
#pragma unroll
      for (int j = 0; j < 8; j++) w0[j] = W[j * 64 + lane];
      float bi = p.ebi[row];
      for (int t = 0; t < TI; t++) {
        const float* x = p.emb + (size_t)p.seq[t] * HH;
        float s = 0.f;
#pragma unroll
        for (int j = 0; j < 8; j++) s += w0[j] * x[j * 64 + lane];
        s = wredf(s);
        if (lane == 0) cstf(&p.gi0[(size_t)t * G3 + row], s + bi);
      }
    }
  }
  bar_arrive(cgA, wg & 7);
  bar_wait8<8>(cgA, 32u);

  // ========== E1: recurrence on KGRU WGs, register weights, 129 barriers ==========
  if (wg < KGRU) {
    float wreg[24][8];  // original j*64+lane mapping (bitwise-preserving)
    if (wv < 2) {
#pragma unroll
      for (int uu = 0; uu < 4; uu++) {
        int u = wg * 8 + wv * 4 + uu;
#pragma unroll
        for (int g = 0; g < 3; g++) {
          const float* W = p.eWh + (size_t)(g * HH + u) * HH;
#pragma unroll
          for (int j = 0; j < 8; j++) wreg[uu * 3 + g][j] = W[j * 64 + lane];
        }
      }
    } else {
#pragma unroll
      for (int uu = 0; uu < 4; uu++) {
        int u = wg * 8 + (wv - 2) * 4 + uu;
#pragma unroll
        for (int g = 0; g < 3; g++) {
          const float* Wi1 = p.eWi + (size_t)G3 * HH + (size_t)(g * HH + u) * HH;
          const float* Wh1 = p.eWh + (size_t)G3 * HH + (size_t)(g * HH + u) * HH;
#pragma unroll
          for (int j = 0; j < 8; j++) {
            wreg[uu * 6 + g][j] = Wi1[j * 64 + lane];
            wreg[uu * 6 + 3 + g][j] = Wh1[j * 64 + lane];
          }
        }
      }
    }
    float* smh0 = sm;        // staged h0b[sIn]  (512)
    float* smh1 = sm + 512;  // staged h1b[sOut] (512)
    for (int T = 0; T <= TI; T++) {
      const int sIn = T & 1, sOut = sIn ^ 1;
      // pair-stage the two h vectors into LDS (1 cld2 each for 256 threads)
      {
        int c = tid << 1;  // pair base col
        float a2[2], b2[2];
        cld2(a2, &p.h0b[sIn * HH + c]);
        cld2(b2, &p.h1b[sOut * HH + c]);
        smh0[c] = a2[0]; smh0[c + 1] = a2[1];
        smh1[c] = b2[0]; smh1[c + 1] = b2[1];
      }
      __syncthreads();
      if (wv < 2) {
        if (T < TI) {
          float hv[8];
#pragma unroll
          for (int j = 0; j < 8; j++) hv[j] = smh0[j * 64 + lane];
          float garr[4][3];
#pragma unroll
          for (int uu = 0; uu < 4; uu++) {
#pragma unroll
            for (int gg = 0; gg < 3; gg++) {
              float s = 0.f;
#pragma unroll
              for (int j = 0; j < 8; j++) s += wreg[uu * 3 + gg][j] * hv[j];
              garr[uu][gg] = wredf(s);
            }
          }
          if (lane == 0) {
            const float* gr = p.gi0 + (size_t)T * G3;
#pragma unroll
            for (int up = 0; up < 2; up++) {
              int u0 = wg * 8 + wv * 4 + up * 2;
              float t_r[2], t_z[2], t_n[2], outv[2];
              cld2(t_r, &gr[u0]); cld2(t_z, &gr[HH + u0]); cld2(t_n, &gr[2 * HH + u0]);
#pragma unroll
              for (int e = 0; e < 2; e++) {
                int uu = up * 2 + e;
                float ir = t_r[e], iz = t_z[e], inn = t_n[e];
                float hr = garr[uu][0] + p.ebh[u0 + e];
                float hz = garr[uu][1] + p.ebh[HH + u0 + e];
                float hn = garr[uu][2] + p.ebh[2 * HH + u0 + e];
                float r = 1.f / (1.f + expf(-(ir + hr)));
                float z = 1.f / (1.f + expf(-(iz + hz)));
                float n = tanhf(inn + r * hn);
                outv[e] = (1.f - z) * n + z * smh0[u0 + e];
              }
              cst2(&p.h0b[sOut * HH + u0], outv[0], outv[1]);
            }
          }
        }
      } else {
        if (T >= 1) {
          float xv[8], hv[8];
#pragma unroll
          for (int j = 0; j < 8; j++) { xv[j] = smh0[j * 64 + lane]; hv[j] = smh1[j * 64 + lane]; }
          float giarr[4][3], gharr[4][3];
#pragma unroll
          for (int uu = 0; uu < 4; uu++) {
#pragma unroll
            for (int gg = 0; gg < 3; gg++) {
              float si = 0.f, s2 = 0.f;
#pragma unroll
              for (int j = 0; j < 8; j++) {
                si += wreg[uu * 6 + gg][j] * xv[j];
                s2 += wreg[uu * 6 + 3 + gg][j] * hv[j];
              }
              giarr[uu][gg] = wredf(si);
              gharr[uu][gg] = wredf(s2);
            }
          }
          if (lane == 0) {
            const float* bi = p.ebi + G3;
            const float* bh = p.ebh + G3;
#pragma unroll
            for (int up = 0; up < 2; up++) {
              int u0 = wg * 8 + (wv - 2) * 4 + up * 2;
              float outv[2];
#pragma unroll
              for (int e = 0; e < 2; e++) {
                int uu = up * 2 + e;
                float ir = giarr[uu][0] + bi[u0 + e], iz = giarr[uu][1] + bi[HH + u0 + e],
                      inn = giarr[uu][2] + bi[2 * HH + u0 + e];
                float hr = gharr[uu][0] + bh[u0 + e], hz = gharr[uu][1] + bh[HH + u0 + e],
                      hn = gharr[uu][2] + bh[2 * HH + u0 + e];
                float r = 1.f / (1.f + expf(-(ir + hr)));
                float z = 1.f / (1.f + expf(-(iz + hz)));
                float n = tanhf(inn + r * hn);
                outv[e] = (1.f - z) * n + z * smh1[u0 + e];
              }
              cst2(&p.h1b[sIn * HH + u0], outv[0], outv[1]);
              cst2(&p.eout[(size_t)(T - 1) * HH + u0], outv[0], outv[1]);
            }
          }
        }
      }
      bar_arrive(ceA, wg & 7);
      bar_wait8<2>(ceA, (unsigned)(8 * (T + 1)));
    }
    if (wg == 0 && tid == 0) bcast_store(feL, 16, 1u);
  } else {
    leaf_wait<16>(feL, wg >> 4, 1u);
  }

  // ---- load decoder GRU weights into registers (KGRU WGs), both layers ----
  float wdec[2][12][8];
  if (wg < KGRU) {
#pragma unroll
    for (int k = 0; k < 12; k++) {
      const int f = wv * 12 + k;
      const int ul = f / 6, m_ = f % 6;
      const int u = wg * 8 + ul;
      const float* W0 = (m_ < 3 ? p.dWi : p.dWh) + (size_t)((m_ % 3) * HH + u) * HH;
      const float* W1 = (m_ < 3 ? p.dWi : p.dWh) + (size_t)G3 * HH + (size_t)((m_ % 3) * HH + u) * HH;
#pragma unroll
      for (int j = 0; j < 8; j++) { wdec[0][k][j] = W0[j * 64 + lane]; wdec[1][k][j] = W1[j * 64 + lane]; }
    }
  }

  // ========== D0: broadcast enc_hidden to beams, init tokens/scores ==========
  {
    for (int i = tid + wg * NTHR; i < 2 * NB * (HH / 2); i += NWG * NTHR) {  // 2560 pairs
      int l = i / (NB * (HH / 2));
      int rem = i - l * (NB * (HH / 2));
      int b = rem >> 8, c = (rem & 255) << 1;
      float h2[2];
      if (l == 0) cld2(h2, &p.h0b[c]); else cld2(h2, &p.h1b[c]);
      cst2(&p.dch[(size_t)l * NB * HH + b * HH + c], h2[0], h2[1]);
    }
    if (wg == 0 && tid < NB) {
      csti(&p.cur_tok[tid], p.sosp[0]);
      cstf(&p.scores[tid], (tid == 0) ? 0.f : NEGF);
    }
  }
  bar_arrive(cgA, wg & 7);
  bar_wait8<8>(cgA, 64u);

  // ========== decoder: 64 steps ==========
  for (int t = 0; t < TO; t++) {
    const int ib = t & 1, ob = ib ^ 1;

    leaf_wait<4>(f6L, wg >> 4, (unsigned)t);  // step-t inputs ready

    if (wg < KGRU) {
      dec_gru_reg<0>(p, sm, t, ib, ob, wdec[0]);
      bar_arrive(c1A, wg & 7);
      bar_wait8<2>(c1A, (unsigned)(8 * (t + 1)));
      dec_gru_reg<1>(p, sm, t, ib, ob, wdec[1]);
      bar_arrive(c2A, wg & 7);
    }

    // ---- PA: attention + ctx + Wc + tanh (40 WGs, 8 per beam) ----
    if (wg < KPA) {
      bar_wait8<2>(c2A, (unsigned)(8 * (t + 1)));
      const int b = wg / 8, q = wg % 8;
      float* srnn = sm;                  // 512
      float* sp = sm + 512;              // 128
      float* cpart = sm + 640;           // [4][512]
      float* sctx = sm + 2688;           // 512
      float* wstg = sm + 3200 + wv * 512;  // wave-private row stage
      for (int i = tid; i < HH / 2; i += NTHR) {
        float r2[2];
        cld2(r2, &p.dch[((size_t)(ob * 2 + 1) * NB + b) * HH + i * 2]);
        srnn[i * 2] = r2[0]; srnn[i * 2 + 1] = r2[1];
      }
      __syncthreads();
      for (int j = wv; j < TI; j += 4) {
        stage_row(wstg, p.eout + (size_t)j * HH, lane);
        float s = 0.f;
#pragma unroll
        for (int k2 = 0; k2 < 8; k2++) s += srnn[k2 * 64 + lane] * wstg[k2 * 64 + lane];
        s = wredf(s);
        if (lane == 0) sp[j] = s;
      }
      __syncthreads();
      if (wv == 0) {
        float v0 = sp[lane], v1 = sp[64 + lane];
        float mx = fmaxf(v0, v1);
#pragma unroll
        for (int o = 32; o; o >>= 1) mx = fmaxf(mx, __shfl_xor(mx, o, 64));
        float e0 = expf(v0 - mx), e1 = expf(v1 - mx);
        float ss = wredf(e0 + e1);
        sp[lane] = e0 / ss;
        sp[64 + lane] = e1 / ss;
      }
      __syncthreads();
      {  // ctx partials, staged rows, original col mapping -> bitwise same
        float cp[8];
#pragma unroll
        for (int k2 = 0; k2 < 8; k2++) cp[k2] = 0.f;
        for (int j = wv; j < TI; j += 4) {
          float spj = sp[j];
          stage_row(wstg, p.eout + (size_t)j * HH, lane);
#pragma unroll
          for (int k2 = 0; k2 < 8; k2++) cp[k2] += spj * wstg[k2 * 64 + lane];
        }
#pragma unroll
        for (int k2 = 0; k2 < 8; k2++) cpart[wv * HH + k2 * 64 + lane] = cp[k2];
      }
      __syncthreads();
      for (int i = tid; i < HH; i += NTHR)
        sctx[i] = ((cpart[0 * HH + i] + cpart[1 * HH + i]) + cpart[2 * HH + i]) + cpart[3 * HH + i];
      __syncthreads();
      for (int k = wv; k < 64; k += 4) {
        int u = q * 64 + k;
        const float* W = p.Wc + (size_t)u * (2 * HH);
        float s0 = 0.f, s1 = 0.f;
#pragma unroll
        for (int j = 0; j < 8; j++) {
          int o = j * 64 + lane;
          s0 += W[o] * srnn[o];
          s1 += W[HH + o] * sctx[o];
        }
        float r0 = wredf(s0), r1 = wredf(s1);
        if (lane == 0) cstf(&p.cc[b * HH + u], tanhf(r0 + r1 + p.bc[u]));
      }
      bar_arrive(c3A, wg & 7);  // 5 arrivals per line
    }
    bar_wait8<4>(c3A, (unsigned)(5 * (t + 1)));

    // ---- P5: logits chunk (125 rows/WG) + per-beam partial top5 + exp-sum ----
    {
      float* scc = sm;            // [NB][HH]
      float* slg = sm + NB * HH;  // [NB][125]
      for (int i = tid; i < NB * (HH / 2); i += NTHR) {
        int b = i >> 8, c = (i & 255) << 1;
        float c2v[2];
        cld2(c2v, &p.cc[b * HH + c]);
        scc[b * HH + c] = c2v[0]; scc[b * HH + c + 1] = c2v[1];
      }
      __syncthreads();
      const int vbase = wg * 125;
      float wnxt[8];
      {
        const float* W = p.Wout + (size_t)(vbase + wv) * HH;
#pragma unroll
        for (int j = 0; j < 8; j++) wnxt[j] = W[j * 64 + lane];
      }
      for (int r = wv; r < 125; r += 4) {
        float wcur[8];
#pragma unroll
        for (int j = 0; j < 8; j++) wcur[j] = wnxt[j];
        if (r + 4 < 125) {
          const float* W2 = p.Wout + (size_t)(vbase + r + 4) * HH;
#pragma unroll
          for (int j = 0; j < 8; j++) wnxt[j] = W2[j * 64 + lane];
        }
        float a0 = 0.f, a1 = 0.f, a2 = 0.f, a3 = 0.f, a4 = 0.f;
#pragma unroll
        for (int j = 0; j < 8; j++) {
          float wj = wcur[j];
          int o = j * 64 + lane;
          a0 += wj * scc[0 * HH + o];
          a1 += wj * scc[1 * HH + o];
          a2 += wj * scc[2 * HH + o];
          a3 += wj * scc[3 * HH + o];
          a4 += wj * scc[4 * HH + o];
        }
        float r0 = wredf(a0), r1 = wredf(a1), r2 = wredf(a2), r3 = wredf(a3), r4 = wredf(a4);
        if (lane == 0) {
          float bo = p.bout[vbase + r];
          slg[0 * 125 + r] = r0 + bo;
          slg[1 * 125 + r] = r1 + bo;
          slg[2 * 125 + r] = r2 + bo;
          slg[3 * 125 + r] = r3 + bo;
          slg[4 * 125 + r] = r4 + bo;
        }
      }
      __syncthreads();
      if (wv == 0) {
        for (int b = 0; b < NB; b++) {
          float s0 = (lane < 125) ? expf(slg[b * 125 + lane]) : 0.f;
          float s1 = (lane + 64 < 125) ? expf(slg[b * 125 + lane + 64]) : 0.f;
          float ss = wredf(s0 + s1);
          if (lane == 0) cstf(&p.psum[wg * NB + b], ss);
        }
      } else if (wv == 1 && lane < NB) {
        int b = lane;
        float bv[5]; int bidx[5];
#pragma unroll
        for (int k = 0; k < 5; k++) { bv[k] = -INFINITY; bidx[k] = 0x7fffffff; }
        for (int r = 0; r < 125; r++) {
          float v = slg[b * 125 + r];
          if (v > bv[4]) {  // strict >: equal values keep earlier (lower) index
            int k = 4;
            while (k > 0 && v > bv[k - 1]) { bv[k] = bv[k - 1]; bidx[k] = bidx[k - 1]; k--; }
            bv[k] = v; bidx[k] = vbase + r;
          }
        }
#pragma unroll
        for (int k = 0; k < 5; k++) {
          cstf(&p.ptop_v[(wg * NB + b) * 5 + k], bv[k]);
          csti(&p.ptop_i[(wg * NB + b) * 5 + k], bidx[k]);
        }
      }
    }

    // ---- last-man selection: final P5 arriver performs the merge ----
    __syncthreads();  // all waves' psum/ptop stores vm-drained (at CP)
    if (tid == 0) {
      unsigned m = 0;
      unsigned o1 = __hip_atomic_fetch_add(c5A + (wg & 7) * LSTR, 1u,
                                           __ATOMIC_RELAXED, __HIP_MEMORY_SCOPE_AGENT);
      if (o1 == (unsigned)(32 * (t + 1) - 1)) {
        unsigned o2 = __hip_atomic_fetch_add(c5F, 1u,
                                             __ATOMIC_RELAXED, __HIP_MEMORY_SCOPE_AGENT);
        if (o2 == (unsigned)(8 * (t + 1) - 1)) m = 1;
      }
      s_mrg = m;
    }
    __syncthreads();

    // ---- P6 merge (performed by the single last-arriving WG) ----
    if (s_mrg) {
      float* sls = sm;               // [5]
      float* smv = sm + 8;           // [5][5]
      int* smi = (int*)(sm + 40);    // [5][5]
      for (int b = wv; b < NB; b += 4) {
        float q0 = cldf(&p.psum[(lane + 0) * NB + b]);
        float q1 = cldf(&p.psum[(lane + 64) * NB + b]);
        float q2 = cldf(&p.psum[(lane + 128) * NB + b]);
        float q3 = cldf(&p.psum[(lane + 192) * NB + b]);
        float ssum = wredf((q0 + q1) + (q2 + q3));
        float bv[5]; int bix[5];
#pragma unroll
        for (int k = 0; k < 5; k++) { bv[k] = -INFINITY; bix[k] = 0x7fffffff; }
        for (int g = 0; g < 4; g++) {
          int w = lane + g * 64;
#pragma unroll
          for (int k = 0; k < 5; k++) {
            float v = cldf(&p.ptop_v[((size_t)w * NB + b) * 5 + k]);
            int id = cldi(&p.ptop_i[((size_t)w * NB + b) * 5 + k]);
            if (v > bv[4] || (v == bv[4] && id < bix[4])) {
              int kk = 4;
              while (kk > 0 && (v > bv[kk - 1] || (v == bv[kk - 1] && id < bix[kk - 1]))) {
                bv[kk] = bv[kk - 1]; bix[kk] = bix[kk - 1]; kk--;
              }
              bv[kk] = v; bix[kk] = id;
            }
          }
        }
#pragma unroll
        for (int off = 1; off < 64; off <<= 1) {
          float ov[5]; int oi[5];
#pragma unroll
          for (int k = 0; k < 5; k++) { ov[k] = __shfl_xor(bv[k], off, 64); oi[k] = __shfl_xor(bix[k], off, 64); }
          float nv[5]; int ni[5];
          int i2 = 0, j2 = 0;
#pragma unroll
          for (int k = 0; k < 5; k++) {
            bool ta = (bv[i2] > ov[j2]) || (bv[i2] == ov[j2] && bix[i2] < oi[j2]);
            if (ta) { nv[k] = bv[i2]; ni[k] = bix[i2]; i2++; }
            else { nv[k] = ov[j2]; ni[k] = oi[j2]; j2++; }
          }
#pragma unroll
          for (int k = 0; k < 5; k++) { bv[k] = nv[k]; bix[k] = ni[k]; }
        }
        if (lane == 0) {
          sls[b] = logf(ssum);
#pragma unroll
          for (int k = 0; k < 5; k++) { smv[b * 5 + k] = bv[k]; smi[b * 5 + k] = bix[k]; }
        }
      }
      __syncthreads();
      if (tid == 0) {
        float cand[25]; int ctok[25];
        for (int b = 0; b < NB; b++) {
          float sb = cldf(&p.scores[b]), lb = sls[b];
#pragma unroll
          for (int k = 0; k < 5; k++) {
            cand[b * 5 + k] = sb + (smv[b * 5 + k] - lb);
            ctok[b * 5 + k] = smi[b * 5 + k];
          }
        }
        float s5[5]; int f5[5];
#pragma unroll
        for (int k = 0; k < 5; k++) { s5[k] = -INFINITY; f5[k] = 0x7fffffff; }
        for (int f = 0; f < 25; f++) {
          float v = cand[f];
          if (v > s5[4]) {
            int k = 4;
            while (k > 0 && v > s5[k - 1]) { s5[k] = s5[k - 1]; f5[k] = f5[k - 1]; k--; }
            s5[k] = v; f5[k] = f;
          }
        }
        for (int j2 = 0; j2 < 5; j2++) {
          int fl = f5[j2];
          csti(&p.pars[t * NB + j2], fl / 5);
          csti(&p.toks[t * NB + j2], ctok[fl]);
          csti(&p.cur_tok[j2], ctok[fl]);
        }
        for (int j2 = 0; j2 < 5; j2++) cstf(&p.scores[j2], s5[j2]);
        bcast_store(f6L, 16, (unsigned)(t + 1));
      }
      __syncthreads();
    }
  }

  // ========== F: backtrack and write output (seq as float, then score) ==========
  if (wg == 0) {
    leaf_wait<4>(f6L, 0, (unsigned)TO);  // final merge (possibly other WG) done
    if (tid == 0) {
      int best = 0;
      float bvv = cldf(&p.scores[0]);
      for (int j = 1; j < NB; j++) {
        float sj = cldf(&p.scores[j]);
        if (sj > bvv) { bvv = sj; best = j; }
      }
      int beam = best;
      for (int tt = TO - 1; tt >= 0; tt--) {
        p.out[tt] = (float)cldi(&p.toks[tt * NB + beam]);
        beam = cldi(&p.pars[tt * NB + beam]);
      }
      p.out[TO] = bvv;
    }
  }
}

extern "C" void kernel_launch(void* const* d_in, const int* in_sizes, int n_in,
                              void* d_out, int out_size, void* d_ws, size_t ws_size,
                              hipStream_t stream) {
  (void)in_sizes; (void)n_in; (void)out_size; (void)ws_size;
  Params p;
  p.seq  = (const int*)d_in[0];
  p.sosp = (const int*)d_in[3];
  p.emb  = (const float*)d_in[4];
  p.eWi  = (const float*)d_in[5];
  p.eWh  = (const float*)d_in[6];
  p.ebi  = (const float*)d_in[7];
  p.ebh  = (const float*)d_in[8];
  p.dWi  = (const float*)d_in[9];
  p.dWh  = (const float*)d_in[10];
  p.dbi  = (const float*)d_in[11];
  p.dbh  = (const float*)d_in[12];
  p.Wc   = (const float*)d_in[13];
  p.bc   = (const float*)d_in[14];
  p.Wout = (const float*)d_in[15];
  p.bout = (const float*)d_in[16];

  char* w = (char*)d_ws;
  size_t off = 0;
  auto alloc = [&](size_t words) -> char* {
    char* r = w + off;
    off += words * 4;
    off = (off + 255) & ~(size_t)255;
    return r;
  };
  p.bar     = (unsigned*)alloc(96 * LSTR);    // 88 lines used (memset below)
  p.cur_tok = (int*)alloc(8);
  p.toks    = (int*)alloc(TO * NB);
  p.pars    = (int*)alloc(TO * NB);
  p.ptop_i  = (int*)alloc(NWG * NB * 5);
  p.gi0     = (float*)alloc((size_t)TI * G3);
  p.eout    = (float*)alloc((size_t)TI * HH);
  p.h0b     = (float*)alloc(2 * HH);
  p.h1b     = (float*)alloc(2 * HH);
  p.dch     = (float*)alloc(2 * 2 * NB * HH);
  p.cc      = (float*)alloc(NB * HH);
  p.ptop_v  = (float*)alloc(NWG * NB * 5);
  p.psum    = (float*)alloc(NWG * NB);
  p.scores  = (float*)alloc(8);
  p.out     = (float*)d_out;

  (void)hipMemsetAsync(d_ws, 0, 96 * LSTR * 4, stream);  // zero all lines
  // Plain launch: 256 WGs x 256 thr at 1 WG/CU on 256 CUs -> co-resident.
  // hipLaunchCooperativeKernel silently rejects at VGPR=256 (r4/r5 failure).
  bsd_kernel<<<dim3(NWG), dim3(NTHR), 0, stream>>>(p);
}